// Round 12
// baseline (1442.014 us; speedup 1.0000x reference)
//
#include <hip/hip_runtime.h>

typedef unsigned short ushort_t;
typedef __attribute__((ext_vector_type(8))) short bf16x8;
typedef __attribute__((ext_vector_type(4))) float f32x4;
typedef __attribute__((ext_vector_type(4))) unsigned short us4;

#define DEV __device__ __forceinline__

DEV ushort_t f2b(float f) {
    union { float f; unsigned u; } x; x.f = f;
    unsigned r = (x.u + 0x7fffu + ((x.u >> 16) & 1u)) >> 16;
    return (ushort_t)r;
}

DEV float b2f(ushort_t u) {
    union { unsigned u; float f; } x; x.u = ((unsigned)u) << 16;
    return x.f;
}

DEV unsigned cvt_pk_bf16(float lo, float hi) {
    unsigned r;
    asm("v_cvt_pk_bf16_f32 %0, %1, %2" : "=v"(r) : "v"(lo), "v"(hi));
    return r;
}

typedef void __attribute__((address_space(1)))* gp1;
typedef void __attribute__((address_space(3)))* sp3;
DEV void gload_lds16(const void* g, void* l) {
    __builtin_amdgcn_global_load_lds((gp1)g, (sp3)l, 16, 0, 0);
}

// ---------------- weight prep: f32 [K][N] -> bf16 [N][K] ----------------
__global__ __launch_bounds__(256) void transpose_cvt(
    const float* __restrict__ in, ushort_t* __restrict__ out, int K, int N)
{
    __shared__ float tile[32][33];
    const int nb = blockIdx.z;
    const float* src = in + (size_t)nb * K * N;
    ushort_t* dst = out + (size_t)nb * K * N;
    const int n0 = blockIdx.x * 32, k0 = blockIdx.y * 32;
    const int tx = threadIdx.x & 31, ty = threadIdx.x >> 5;
#pragma unroll
    for (int i = 0; i < 32; i += 8)
        tile[ty + i][tx] = src[(size_t)(k0 + ty + i) * N + n0 + tx];
    __syncthreads();
#pragma unroll
    for (int i = 0; i < 32; i += 8)
        dst[(size_t)(n0 + ty + i) * K + k0 + tx] = f2b(tile[tx][ty + i]);
}

// ---------------- init: X f32 -> xf f32 copy + xb bf16 ----------------
__global__ __launch_bounds__(256) void init_x(
    const float* __restrict__ X, float* __restrict__ xf, ushort_t* __restrict__ xb)
{
    const int i = blockIdx.x * 256 + threadIdx.x;
    const float4 v = ((const float4*)X)[i];
    ((float4*)xf)[i] = v;
    us4 o = { f2b(v.x), f2b(v.y), f2b(v.z), f2b(v.w) };
    ((us4*)xb)[i] = o;
}

enum { EPI_QKV = 0, EPI_RELUB = 2 };

// ---------------- GEMM 64x128 tile, BK=64 (QKV / MLP1) ---------------------
template<int EPI>
__global__ __launch_bounds__(256, 3) void gemm64(
    const ushort_t* __restrict__ A, const ushort_t* __restrict__ Wt,
    const float* __restrict__ bias, ushort_t* __restrict__ Cb,
    ushort_t* __restrict__ Oq, ushort_t* __restrict__ Ok, ushort_t* __restrict__ Ov,
    int M, int N, int K, float qs)
{
    __shared__ __align__(16) ushort_t lA[2][64 * 64];
    __shared__ __align__(16) ushort_t lB[2][128 * 64];
    const int nbm = M >> 6;
    const int bm = blockIdx.x % nbm;
    const int bn = blockIdx.x / nbm;
    const int tid = threadIdx.x, lane = tid & 63, w = tid >> 6;
    const int l15 = lane & 15, l4 = lane >> 4;

    f32x4 acc[4][2];
#pragma unroll
    for (int i = 0; i < 4; i++)
#pragma unroll
        for (int j = 0; j < 2; j++) { f32x4 z = {0.f, 0.f, 0.f, 0.f}; acc[i][j] = z; }

    const int srow = tid >> 3;
    const int sch = tid & 7;
    const int swch = sch ^ (srow & 7);
    const ushort_t* Asrc0 = A  + (size_t)(bm * 64 + srow) * K + swch * 8;
    const ushort_t* Asrc1 = A  + (size_t)(bm * 64 + srow + 32) * K + swch * 8;
    const ushort_t* Bsrc0 = Wt + (size_t)(bn * 128 + srow) * K + swch * 8;
    const ushort_t* Bsrc1 = Wt + (size_t)(bn * 128 + srow + 32) * K + swch * 8;
    const ushort_t* Bsrc2 = Wt + (size_t)(bn * 128 + srow + 64) * K + swch * 8;
    const ushort_t* Bsrc3 = Wt + (size_t)(bn * 128 + srow + 96) * K + swch * 8;
    char* lAc = (char*)lA;
    char* lBc = (char*)lB;

#define GE_STAGE(buf, k0) do {                                            \
        gload_lds16(Asrc0 + (k0), lAc + (buf) * 8192  + w * 1024);        \
        gload_lds16(Asrc1 + (k0), lAc + (buf) * 8192  + 4096 + w * 1024); \
        gload_lds16(Bsrc0 + (k0), lBc + (buf) * 16384 + w * 1024);        \
        gload_lds16(Bsrc1 + (k0), lBc + (buf) * 16384 + 4096 + w * 1024); \
        gload_lds16(Bsrc2 + (k0), lBc + (buf) * 16384 + 8192 + w * 1024); \
        gload_lds16(Bsrc3 + (k0), lBc + (buf) * 16384 + 12288 + w * 1024);\
    } while (0)

    GE_STAGE(0, 0);
    __syncthreads();

    const int nIt = K >> 6;
    int cur = 0;
    for (int it = 0; it < nIt; ++it) {
        if (it + 1 < nIt) GE_STAGE(cur ^ 1, (it + 1) * 64);
#pragma unroll
        for (int ks = 0; ks < 2; ks++) {
            bf16x8 af[4], bfr[2];
#pragma unroll
            for (int i = 0; i < 4; i++) {
                const int row = i * 16 + l15;
                af[i] = *(const bf16x8*)(lAc + cur * 8192 + row * 128 +
                                         (((ks * 4 + l4) ^ (row & 7)) << 4));
            }
#pragma unroll
            for (int j = 0; j < 2; j++) {
                const int row = w * 32 + j * 16 + l15;
                bfr[j] = *(const bf16x8*)(lBc + cur * 16384 + row * 128 +
                                          (((ks * 4 + l4) ^ (row & 7)) << 4));
            }
#pragma unroll
            for (int i = 0; i < 4; i++)
#pragma unroll
                for (int j = 0; j < 2; j++)
                    acc[i][j] = __builtin_amdgcn_mfma_f32_16x16x32_bf16(af[i], bfr[j], acc[i][j], 0, 0, 0);
        }
        __syncthreads();
        cur ^= 1;
    }
#undef GE_STAGE

    const int mbase = bm * 64;
    const int nbase = bn * 128 + w * 32;
#pragma unroll
    for (int j = 0; j < 2; j++) {
        const int nf16 = nbase + j * 16;
        const float bv = bias[nf16 + l15];
        if constexpr (EPI == EPI_QKV) {
            const int head = nf16 / 192;
            const int rem = nf16 - head * 192;
            const int part = rem >> 6;
            const int dh = (rem & 63) + l15;
#pragma unroll
            for (int i = 0; i < 4; i++) {
                const int m0 = mbase + i * 16 + l4 * 4;
                const int b = m0 >> 11, s0 = m0 & 2047;
                if (part == 2) {
                    us4 pv;
#pragma unroll
                    for (int r = 0; r < 4; r++) pv[r] = f2b(acc[i][j][r] + bv);
                    *(us4*)(&Ov[((size_t)(b * 8 + head) * 64 + dh) * 2048 + s0]) = pv;
                } else if (part == 0) {
#pragma unroll
                    for (int r = 0; r < 4; r++)
                        Oq[((size_t)(b * 8 + head) * 2048 + s0 + r) * 64 + dh] =
                            f2b((acc[i][j][r] + bv) * qs);
                } else {
#pragma unroll
                    for (int r = 0; r < 4; r++)
                        Ok[((size_t)(b * 8 + head) * 2048 + s0 + r) * 64 + dh] =
                            f2b(acc[i][j][r] + bv);
                }
            }
        } else {
#pragma unroll
            for (int i = 0; i < 4; i++) {
                const int m0 = mbase + i * 16 + l4 * 4;
#pragma unroll
                for (int r = 0; r < 4; r++) {
                    const size_t idx = (size_t)(m0 + r) * N + nf16 + l15;
                    const float v = acc[i][j][r] + bv;
                    Cb[idx] = f2b(v > 0.f ? v : 0.f);
                }
            }
        }
    }
}

// ---------------- GEMM 64x128, split-K=2, writes bf16 partials --------------
__global__ __launch_bounds__(256, 2) void gemm64_splitk(
    const ushort_t* __restrict__ A, const ushort_t* __restrict__ Wt,
    ushort_t* __restrict__ P0, ushort_t* __restrict__ P1, int M, int N, int K)
{
    __shared__ __align__(16) ushort_t lA[2][64 * 64];
    __shared__ __align__(16) ushort_t lB[2][128 * 64];
    const int nbm = M >> 6;
    const int nbn = N >> 7;
    int bid = blockIdx.x;
    const int bm = bid % nbm; bid /= nbm;
    const int bn = bid % nbn;
    const int kh = bid / nbn;
    const int Keff = K >> 1;
    const int kbase = kh * Keff;
    const int tid = threadIdx.x, lane = tid & 63, w = tid >> 6;
    const int l15 = lane & 15, l4 = lane >> 4;

    f32x4 acc[4][2];
#pragma unroll
    for (int i = 0; i < 4; i++)
#pragma unroll
        for (int j = 0; j < 2; j++) { f32x4 z = {0.f, 0.f, 0.f, 0.f}; acc[i][j] = z; }

    const int srow = tid >> 3;
    const int sch = tid & 7;
    const int swch = sch ^ (srow & 7);
    const ushort_t* Asrc0 = A  + (size_t)(bm * 64 + srow) * K + kbase + swch * 8;
    const ushort_t* Asrc1 = A  + (size_t)(bm * 64 + srow + 32) * K + kbase + swch * 8;
    const ushort_t* Bsrc0 = Wt + (size_t)(bn * 128 + srow) * K + kbase + swch * 8;
    const ushort_t* Bsrc1 = Wt + (size_t)(bn * 128 + srow + 32) * K + kbase + swch * 8;
    const ushort_t* Bsrc2 = Wt + (size_t)(bn * 128 + srow + 64) * K + kbase + swch * 8;
    const ushort_t* Bsrc3 = Wt + (size_t)(bn * 128 + srow + 96) * K + kbase + swch * 8;
    char* lAc = (char*)lA;
    char* lBc = (char*)lB;

#define GE_STAGE(buf, k0) do {                                            \
        gload_lds16(Asrc0 + (k0), lAc + (buf) * 8192  + w * 1024);        \
        gload_lds16(Asrc1 + (k0), lAc + (buf) * 8192  + 4096 + w * 1024); \
        gload_lds16(Bsrc0 + (k0), lBc + (buf) * 16384 + w * 1024);        \
        gload_lds16(Bsrc1 + (k0), lBc + (buf) * 16384 + 4096 + w * 1024); \
        gload_lds16(Bsrc2 + (k0), lBc + (buf) * 16384 + 8192 + w * 1024); \
        gload_lds16(Bsrc3 + (k0), lBc + (buf) * 16384 + 12288 + w * 1024);\
    } while (0)

    GE_STAGE(0, 0);
    __syncthreads();

    const int nIt = Keff >> 6;
    int cur = 0;
    for (int it = 0; it < nIt; ++it) {
        if (it + 1 < nIt) GE_STAGE(cur ^ 1, (it + 1) * 64);
#pragma unroll
        for (int ks = 0; ks < 2; ks++) {
            bf16x8 af[4], bfr[2];
#pragma unroll
            for (int i = 0; i < 4; i++) {
                const int row = i * 16 + l15;
                af[i] = *(const bf16x8*)(lAc + cur * 8192 + row * 128 +
                                         (((ks * 4 + l4) ^ (row & 7)) << 4));
            }
#pragma unroll
            for (int j = 0; j < 2; j++) {
                const int row = w * 32 + j * 16 + l15;
                bfr[j] = *(const bf16x8*)(lBc + cur * 16384 + row * 128 +
                                          (((ks * 4 + l4) ^ (row & 7)) << 4));
            }
#pragma unroll
            for (int i = 0; i < 4; i++)
#pragma unroll
                for (int j = 0; j < 2; j++)
                    acc[i][j] = __builtin_amdgcn_mfma_f32_16x16x32_bf16(af[i], bfr[j], acc[i][j], 0, 0, 0);
        }
        __syncthreads();
        cur ^= 1;
    }
#undef GE_STAGE

    ushort_t* out = kh ? P1 : P0;
    const int mbase = bm * 64;
    const int nbase = bn * 128 + w * 32;
#pragma unroll
    for (int j = 0; j < 2; j++) {
        const int nf16 = nbase + j * 16;
#pragma unroll
        for (int i = 0; i < 4; i++) {
            const int m0 = mbase + i * 16 + l4 * 4;
#pragma unroll
            for (int r = 0; r < 4; r++)
                out[(size_t)(m0 + r) * N + nf16 + l15] = f2b(acc[i][j][r]);
        }
    }
}

// ---------------- flash attention v12: v7 verbatim, no KV split ------------
// Full KV per block, 512 blocks (32 qt x 16 bh), normalize + write O direct.
// No max-tracking; Q pre-scaled by scale*log2(e). niter runtime (anti-unroll).
// Q,K: [16][2048][64] bf16 ; Vt: [16][64][2048] bf16 ; O: [4096][512] bf16
__global__ __launch_bounds__(256, 4) void flash_attn12(
    const ushort_t* __restrict__ Q, const ushort_t* __restrict__ Kg,
    const ushort_t* __restrict__ Vg, ushort_t* __restrict__ O, int niter)
{
    __shared__ __align__(16) ushort_t lK[2][64 * 64];   // 16 KB
    __shared__ __align__(16) ushort_t lV[2][64 * 64];   // 16 KB
    __shared__ __align__(16) ushort_t lP[4][32 * 64];   // 16 KB -> 48 KB

    // id bits: [bh_hi:1][qt:5][bh_lo:3]
    const int id = blockIdx.x;
    const int rest = id >> 3;
    const int qt = rest & 31;
    const int bh = (id & 7) + ((rest >> 5) << 3);
    const int tid = threadIdx.x, lane = tid & 63, w = tid >> 6;
    const int l15 = lane & 15, l4 = lane >> 4;
    const int qrow0 = qt * 64 + w * 16;   // 16 q-rows per wave per qi... (2 qi => 32)
    const int qbase = qt * 128 + w * 32;  // 32 q-rows/wave, 128/block

    const ushort_t* Qb = Q + ((size_t)bh * 2048 + qbase) * 64;
    bf16x8 qf[2][2];
#pragma unroll
    for (int qi = 0; qi < 2; qi++)
#pragma unroll
        for (int ks = 0; ks < 2; ks++)
            qf[qi][ks] = *(const bf16x8*)(Qb + (qi * 16 + l15) * 64 + ks * 32 + l4 * 8);
    (void)qrow0;

    const ushort_t* Kbase = Kg + (size_t)bh * 2048 * 64;
    const ushort_t* Vbase = Vg + (size_t)bh * 64 * 2048;

    const f32x4 FZ = { 0.f, 0.f, 0.f, 0.f };
    float l_run[2] = { 0.f, 0.f };
    f32x4 oacc[2][4];
#pragma unroll
    for (int qi = 0; qi < 2; qi++)
#pragma unroll
        for (int nd = 0; nd < 4; nd++) oacc[qi][nd] = FZ;

    char* lKc = (char*)lK;
    char* lVc = (char*)lV;
    char* myP = (char*)(lP[w]);

    const int srow8 = lane >> 3;
    const int sch = lane & 7;

#define FA_STAGE(buf, kt) do {                                              \
        const int row0_ = w * 16 + srow8;                                   \
        const int sc0_ = sch ^ (row0_ & 7);                                 \
        gload_lds16(Kbase + (size_t)((kt) * 64 + row0_) * 64 + sc0_ * 8,    \
                    lKc + (buf) * 8192 + w * 2048);                         \
        gload_lds16(Vbase + (size_t)row0_ * 2048 + (kt) * 64 + sc0_ * 8,    \
                    lVc + (buf) * 8192 + w * 2048);                         \
        gload_lds16(Kbase + (size_t)((kt) * 64 + row0_ + 8) * 64 + sc0_ * 8,\
                    lKc + (buf) * 8192 + w * 2048 + 1024);                  \
        gload_lds16(Vbase + (size_t)(row0_ + 8) * 2048 + (kt) * 64 + sc0_ * 8,\
                    lVc + (buf) * 8192 + w * 2048 + 1024);                  \
    } while (0)

// v7 body verbatim.
#define FA_BODY(CUR, IT, LIM) do {                                          \
    if ((IT) < (LIM)) FA_STAGE((CUR) ^ 1, (IT) + 1);                        \
    f32x4 sc[2][4];                                                         \
    __builtin_amdgcn_s_setprio(1);                                          \
    _Pragma("unroll")                                                       \
    for (int nf = 0; nf < 4; nf++) {                                        \
        const int krow = nf * 16 + l15;                                     \
        const bf16x8 kf0 = *(const bf16x8*)(lKc + (CUR) * 8192 + krow * 128 + \
                                            ((l4 ^ (krow & 7)) << 4));      \
        const bf16x8 kf1 = *(const bf16x8*)(lKc + (CUR) * 8192 + krow * 128 + \
                                            (((4 + l4) ^ (krow & 7)) << 4)); \
        sc[0][nf] = __builtin_amdgcn_mfma_f32_16x16x32_bf16(kf0, qf[0][0], FZ, 0, 0, 0); \
        sc[1][nf] = __builtin_amdgcn_mfma_f32_16x16x32_bf16(kf0, qf[1][0], FZ, 0, 0, 0); \
        sc[0][nf] = __builtin_amdgcn_mfma_f32_16x16x32_bf16(kf1, qf[0][1], sc[0][nf], 0, 0, 0); \
        sc[1][nf] = __builtin_amdgcn_mfma_f32_16x16x32_bf16(kf1, qf[1][1], sc[1][nf], 0, 0, 0); \
    }                                                                       \
    __builtin_amdgcn_s_setprio(0);                                          \
    _Pragma("unroll")                                                       \
    for (int qi = 0; qi < 2; qi++) {                                        \
        float ps0 = 0.f, ps1 = 0.f;                                         \
        _Pragma("unroll")                                                   \
        for (int nf = 0; nf < 4; nf++) {                                    \
            const float p0 = exp2f(sc[qi][nf][0]);                          \
            const float p1 = exp2f(sc[qi][nf][1]);                          \
            const float p2 = exp2f(sc[qi][nf][2]);                          \
            const float p3 = exp2f(sc[qi][nf][3]);                          \
            sc[qi][nf][0] = p0; sc[qi][nf][1] = p1;                         \
            sc[qi][nf][2] = p2; sc[qi][nf][3] = p3;                         \
            ps0 += p0 + p2; ps1 += p1 + p3;                                 \
        }                                                                   \
        l_run[qi] += ps0 + ps1;                                             \
    }                                                                       \
    const int hh0 = (l15 >> 3) & 1;                                         \
    _Pragma("unroll")                                                       \
    for (int qi = 0; qi < 2; qi++) {                                        \
        char* rp = myP + (qi * 16 + l15) * 128;                             \
        const int swz = (l15 & 7) << 4;                                     \
        _Pragma("unroll")                                                   \
        for (int nf = 0; nf < 4; nf++) {                                    \
            const unsigned pw0 = cvt_pk_bf16(sc[qi][nf][0], sc[qi][nf][1]); \
            const unsigned pw1 = cvt_pk_bf16(sc[qi][nf][2], sc[qi][nf][3]); \
            const unsigned wA = hh0 ? pw1 : pw0;                            \
            const unsigned wB = hh0 ? pw0 : pw1;                            \
            const int cbase = nf * 32 + l4 * 8;                             \
            *(unsigned*)(rp + ((cbase + hh0 * 4) ^ swz)) = wA;              \
            *(unsigned*)(rp + ((cbase + (1 - hh0) * 4) ^ swz)) = wB;        \
        }                                                                   \
    }                                                                       \
    __asm__ volatile("" ::: "memory");                                     \
    bf16x8 pa[2][2];                                                        \
    _Pragma("unroll")                                                       \
    for (int qi = 0; qi < 2; qi++)                                          \
        _Pragma("unroll")                                                   \
        for (int ks = 0; ks < 2; ks++)                                      \
            pa[qi][ks] = *(const bf16x8*)(myP + (qi * 16 + l15) * 128 +     \
                                          ((ks * 64 + l4 * 16) ^ ((l15 & 7) << 4))); \
    __builtin_amdgcn_s_setprio(1);                                          \
    _Pragma("unroll")                                                       \
    for (int ks = 0; ks < 2; ks++)                                          \
        _Pragma("unroll")                                                   \
        for (int nd = 0; nd < 4; nd++) {                                    \
            const int vrow = nd * 16 + l15;                                 \
            const bf16x8 vf = *(const bf16x8*)(lVc + (CUR) * 8192 + vrow * 128 + \
                                               (((ks * 4 + l4) ^ (vrow & 7)) << 4)); \
            oacc[0][nd] = __builtin_amdgcn_mfma_f32_16x16x32_bf16(pa[0][ks], vf, oacc[0][nd], 0, 0, 0); \
            oacc[1][nd] = __builtin_amdgcn_mfma_f32_16x16x32_bf16(pa[1][ks], vf, oacc[1][nd], 0, 0, 0); \
        }                                                                   \
    __builtin_amdgcn_s_setprio(0);                                          \
    __syncthreads();                                                        \
} while (0)

    FA_STAGE(0, 0);
    __syncthreads();

    const int lim = niter * 2 - 1;
#pragma unroll 1
    for (int it2 = 0; it2 < niter; ++it2) {
        FA_BODY(0, it2 * 2, lim);
        FA_BODY(1, it2 * 2 + 1, lim);
    }
#undef FA_BODY
#undef FA_STAGE

    // epilogue: complete l, normalize, write O directly
#pragma unroll
    for (int qi = 0; qi < 2; qi++) {
        l_run[qi] += __shfl_xor(l_run[qi], 16);
        l_run[qi] += __shfl_xor(l_run[qi], 32);
    }
    const int bq = bh >> 3, hh = bh & 7;
#pragma unroll
    for (int qi = 0; qi < 2; qi++) {
#pragma unroll
        for (int r = 0; r < 4; r++) {
            const float lv = __shfl(l_run[qi], l4 * 4 + r);
            const float inv = 1.f / lv;
            const int s = qbase + qi * 16 + l4 * 4 + r;
#pragma unroll
            for (int nd = 0; nd < 4; nd++)
                O[((size_t)(bq * 2048 + s)) * 512 + hh * 64 + nd * 16 + l15] =
                    f2b(oacc[qi][nd][r] * inv);
        }
    }
}

// ------- fused: x' = xf + p0 + p1 + bias ; y = LN(x') (bf16 partials) ------
template<int CN>
__global__ __launch_bounds__(256) void ln_fused(
    const float* __restrict__ Xf, const ushort_t* __restrict__ P0,
    const ushort_t* __restrict__ P1, const float* __restrict__ bias,
    const float* __restrict__ g, const float* __restrict__ beta,
    float* __restrict__ XfOut, ushort_t* __restrict__ Yb, float* __restrict__ Yf)
{
    const int row = blockIdx.x * 4 + (threadIdx.x >> 6);
    const int lane = threadIdx.x & 63;
    const size_t base = (size_t)row * 512;
    float4 x0 = ((const float4*)(Xf + base))[lane];
    float4 x1 = ((const float4*)(Xf + base))[lane + 64];
    const us4 a0 = ((const us4*)(P0 + base))[lane];
    const us4 a1 = ((const us4*)(P0 + base))[lane + 64];
    const us4 c0 = ((const us4*)(P1 + base))[lane];
    const us4 c1 = ((const us4*)(P1 + base))[lane + 64];
    const float4 bb0 = ((const float4*)bias)[lane];
    const float4 bb1 = ((const float4*)bias)[lane + 64];
    x0.x += b2f(a0[0]) + b2f(c0[0]) + bb0.x; x0.y += b2f(a0[1]) + b2f(c0[1]) + bb0.y;
    x0.z += b2f(a0[2]) + b2f(c0[2]) + bb0.z; x0.w += b2f(a0[3]) + b2f(c0[3]) + bb0.w;
    x1.x += b2f(a1[0]) + b2f(c1[0]) + bb1.x; x1.y += b2f(a1[1]) + b2f(c1[1]) + bb1.y;
    x1.z += b2f(a1[2]) + b2f(c1[2]) + bb1.z; x1.w += b2f(a1[3]) + b2f(c1[3]) + bb1.w;

    float s = x0.x + x0.y + x0.z + x0.w + x1.x + x1.y + x1.z + x1.w;
    float s2 = x0.x * x0.x + x0.y * x0.y + x0.z * x0.z + x0.w * x0.w
             + x1.x * x1.x + x1.y * x1.y + x1.z * x1.z + x1.w * x1.w;
#pragma unroll
    for (int m = 1; m < 64; m <<= 1) { s += __shfl_xor(s, m); s2 += __shfl_xor(s2, m); }
    const float mean = s * (1.f / 512.f);
    const float inv = rsqrtf(s2 * (1.f / 512.f) - mean * mean + 1e-5f);
    const float4 g0 = ((const float4*)g)[lane], g1 = ((const float4*)g)[lane + 64];
    const float4 b0 = ((const float4*)beta)[lane], b1 = ((const float4*)beta)[lane + 64];
    float4 y0, y1;
    y0.x = (x0.x - mean) * inv * g0.x + b0.x;
    y0.y = (x0.y - mean) * inv * g0.y + b0.y;
    y0.z = (x0.z - mean) * inv * g0.z + b0.z;
    y0.w = (x0.w - mean) * inv * g0.w + b0.w;
    y1.x = (x1.x - mean) * inv * g1.x + b1.x;
    y1.y = (x1.y - mean) * inv * g1.y + b1.y;
    y1.z = (x1.z - mean) * inv * g1.z + b1.z;
    y1.w = (x1.w - mean) * inv * g1.w + b1.w;
    if constexpr (CN == 0) {
        ((float4*)(XfOut + base))[lane] = x0;
        ((float4*)(XfOut + base))[lane + 64] = x1;
    } else {
        ((float4*)(XfOut + base))[lane] = y0;
        ((float4*)(XfOut + base))[lane + 64] = y1;
        if (Yf) {
            ((float4*)(Yf + base))[lane] = y0;
            ((float4*)(Yf + base))[lane + 64] = y1;
        }
    }
    us4 o0 = { f2b(y0.x), f2b(y0.y), f2b(y0.z), f2b(y0.w) };
    us4 o1 = { f2b(y1.x), f2b(y1.y), f2b(y1.z), f2b(y1.w) };
    ((us4*)(Yb + base))[lane] = o0;
    ((us4*)(Yb + base))[lane + 64] = o1;
}

// ---------------- host ----------------
extern "C" void kernel_launch(void* const* d_in, const int* in_sizes, int n_in,
                              void* d_out, int out_size, void* d_ws, size_t ws_size,
                              hipStream_t stream)
{
    (void)in_sizes; (void)n_in; (void)out_size; (void)ws_size;
    const float* X     = (const float*)d_in[0];
    const float* qkv_w = (const float*)d_in[1];
    const float* qkv_b = (const float*)d_in[2];
    const float* fc_w  = (const float*)d_in[3];
    const float* fc_b  = (const float*)d_in[4];
    const float* ln1_g = (const float*)d_in[5];
    const float* ln1_b = (const float*)d_in[6];
    const float* w1    = (const float*)d_in[7];
    const float* b1    = (const float*)d_in[8];
    const float* w2    = (const float*)d_in[9];
    const float* b2    = (const float*)d_in[10];
    const float* ln2_g = (const float*)d_in[11];
    const float* ln2_b = (const float*)d_in[12];

    char* ws = (char*)d_ws;
    size_t off = 0;
    auto alloc = [&](size_t bytes) -> char* {
        char* p = ws + off;
        off += (bytes + 255) & ~(size_t)255;
        return p;
    };
    ushort_t* qkvw_t = (ushort_t*)alloc(12ull * 1536 * 512 * 2);
    ushort_t* fcw_t  = (ushort_t*)alloc(12ull * 512 * 512 * 2);
    ushort_t* w1_t   = (ushort_t*)alloc(12ull * 512 * 1024 * 2);
    ushort_t* w2_t   = (ushort_t*)alloc(12ull * 1024 * 512 * 2);
    float*    xf     = (float*)   alloc(4096ull * 512 * 4);
    ushort_t* xb     = (ushort_t*)alloc(4096ull * 512 * 2);
    ushort_t* qb     = (ushort_t*)alloc(16ull * 2048 * 64 * 2);   // 4 MB
    ushort_t* kb     = (ushort_t*)alloc(16ull * 2048 * 64 * 2);   // 4 MB
    ushort_t* vt     = (ushort_t*)alloc(16ull * 64 * 2048 * 2);
    ushort_t* ob     = (ushort_t*)alloc(4096ull * 512 * 2);
    ushort_t* y1     = (ushort_t*)alloc(4096ull * 512 * 2);
    ushort_t* hbuf   = (ushort_t*)alloc(4096ull * 1024 * 2);
    // split-K bf16 partials alias qb/kb (dead between flash-consume and next QKV)
    ushort_t* pk0 = qb;
    ushort_t* pk1 = kb;

    transpose_cvt<<<dim3(48, 16, 12), 256, 0, stream>>>(qkv_w, qkvw_t, 512, 1536);
    transpose_cvt<<<dim3(16, 16, 12), 256, 0, stream>>>(fc_w, fcw_t, 512, 512);
    transpose_cvt<<<dim3(32, 16, 12), 256, 0, stream>>>(w1, w1_t, 512, 1024);
    transpose_cvt<<<dim3(16, 32, 12), 256, 0, stream>>>(w2, w2_t, 1024, 512);
    init_x<<<2048, 256, 0, stream>>>(X, xf, xb);

    const float sl2 = (float)(0.044194173824159216 * 1.4426950408889634); // scale*log2(e)
    for (int nb = 0; nb < 12; nb++) {
        gemm64<EPI_QKV><<<64 * 12, 256, 0, stream>>>(
            xb, qkvw_t + (size_t)nb * 1536 * 512, qkv_b + nb * 1536,
            nullptr, qb, kb, vt, 4096, 1536, 512, sl2);
        flash_attn12<<<512, 256, 0, stream>>>(qb, kb, vt, ob, 16);
        gemm64_splitk<<<64 * 4 * 2, 256, 0, stream>>>(
            ob, fcw_t + (size_t)nb * 512 * 512, pk0, pk1, 4096, 512, 512);
        ln_fused<0><<<1024, 256, 0, stream>>>(
            xf, pk0, pk1, fc_b + nb * 512, ln1_g + nb * 512, ln1_b + nb * 512,
            xf, y1, nullptr);
        gemm64<EPI_RELUB><<<64 * 8, 256, 0, stream>>>(
            y1, w1_t + (size_t)nb * 1024 * 512, b1 + nb * 1024,
            hbuf, nullptr, nullptr, nullptr, 4096, 1024, 512, 1.f);
        gemm64_splitk<<<64 * 4 * 2, 256, 0, stream>>>(
            hbuf, w2_t + (size_t)nb * 1024 * 512, pk0, pk1, 4096, 512, 1024);
        ln_fused<1><<<1024, 256, 0, stream>>>(
            xf, pk0, pk1, b2 + nb * 512, ln2_g + nb * 512, ln2_b + nb * 512,
            xf, xb, nb == 11 ? (float*)d_out : nullptr);
    }
}

// Round 13
// 1151.957 us; speedup vs baseline: 1.2518x; 1.2518x over previous
//
#include <hip/hip_runtime.h>

typedef unsigned short ushort_t;
typedef __attribute__((ext_vector_type(8))) short bf16x8;
typedef __attribute__((ext_vector_type(4))) float f32x4;
typedef __attribute__((ext_vector_type(4))) unsigned short us4;

#define DEV __device__ __forceinline__

DEV ushort_t f2b(float f) {
    union { float f; unsigned u; } x; x.f = f;
    unsigned r = (x.u + 0x7fffu + ((x.u >> 16) & 1u)) >> 16;
    return (ushort_t)r;
}

DEV float b2f(ushort_t u) {
    union { unsigned u; float f; } x; x.u = ((unsigned)u) << 16;
    return x.f;
}

DEV unsigned cvt_pk_bf16(float lo, float hi) {
    unsigned r;
    asm("v_cvt_pk_bf16_f32 %0, %1, %2" : "=v"(r) : "v"(lo), "v"(hi));
    return r;
}

typedef void __attribute__((address_space(1)))* gp1;
typedef void __attribute__((address_space(3)))* sp3;
DEV void gload_lds16(const void* g, void* l) {
    __builtin_amdgcn_global_load_lds((gp1)g, (sp3)l, 16, 0, 0);
}

// ---------------- weight prep: f32 [K][N] -> bf16 [N][K] ----------------
__global__ __launch_bounds__(256) void transpose_cvt(
    const float* __restrict__ in, ushort_t* __restrict__ out, int K, int N)
{
    __shared__ float tile[32][33];
    const int nb = blockIdx.z;
    const float* src = in + (size_t)nb * K * N;
    ushort_t* dst = out + (size_t)nb * K * N;
    const int n0 = blockIdx.x * 32, k0 = blockIdx.y * 32;
    const int tx = threadIdx.x & 31, ty = threadIdx.x >> 5;
#pragma unroll
    for (int i = 0; i < 32; i += 8)
        tile[ty + i][tx] = src[(size_t)(k0 + ty + i) * N + n0 + tx];
    __syncthreads();
#pragma unroll
    for (int i = 0; i < 32; i += 8)
        dst[(size_t)(n0 + ty + i) * K + k0 + tx] = f2b(tile[tx][ty + i]);
}

// ---------------- init: X f32 -> xf f32 copy + xb bf16 ----------------
__global__ __launch_bounds__(256) void init_x(
    const float* __restrict__ X, float* __restrict__ xf, ushort_t* __restrict__ xb)
{
    const int i = blockIdx.x * 256 + threadIdx.x;
    const float4 v = ((const float4*)X)[i];
    ((float4*)xf)[i] = v;
    us4 o = { f2b(v.x), f2b(v.y), f2b(v.z), f2b(v.w) };
    ((us4*)xb)[i] = o;
}

enum { EPI_QKV = 0, EPI_RELUB = 2 };

// ---------------- GEMM 64x128 tile, BK=64 (QKV / MLP1) ---------------------
template<int EPI>
__global__ __launch_bounds__(256, 3) void gemm64(
    const ushort_t* __restrict__ A, const ushort_t* __restrict__ Wt,
    const float* __restrict__ bias, ushort_t* __restrict__ Cb,
    ushort_t* __restrict__ Oq, ushort_t* __restrict__ Ok, ushort_t* __restrict__ Ov,
    int M, int N, int K, float qs)
{
    __shared__ __align__(16) ushort_t lA[2][64 * 64];
    __shared__ __align__(16) ushort_t lB[2][128 * 64];
    const int nbm = M >> 6;
    const int bm = blockIdx.x % nbm;
    const int bn = blockIdx.x / nbm;
    const int tid = threadIdx.x, lane = tid & 63, w = tid >> 6;
    const int l15 = lane & 15, l4 = lane >> 4;

    f32x4 acc[4][2];
#pragma unroll
    for (int i = 0; i < 4; i++)
#pragma unroll
        for (int j = 0; j < 2; j++) { f32x4 z = {0.f, 0.f, 0.f, 0.f}; acc[i][j] = z; }

    const int srow = tid >> 3;
    const int sch = tid & 7;
    const int swch = sch ^ (srow & 7);
    const ushort_t* Asrc0 = A  + (size_t)(bm * 64 + srow) * K + swch * 8;
    const ushort_t* Asrc1 = A  + (size_t)(bm * 64 + srow + 32) * K + swch * 8;
    const ushort_t* Bsrc0 = Wt + (size_t)(bn * 128 + srow) * K + swch * 8;
    const ushort_t* Bsrc1 = Wt + (size_t)(bn * 128 + srow + 32) * K + swch * 8;
    const ushort_t* Bsrc2 = Wt + (size_t)(bn * 128 + srow + 64) * K + swch * 8;
    const ushort_t* Bsrc3 = Wt + (size_t)(bn * 128 + srow + 96) * K + swch * 8;
    char* lAc = (char*)lA;
    char* lBc = (char*)lB;

#define GE_STAGE(buf, k0) do {                                            \
        gload_lds16(Asrc0 + (k0), lAc + (buf) * 8192  + w * 1024);        \
        gload_lds16(Asrc1 + (k0), lAc + (buf) * 8192  + 4096 + w * 1024); \
        gload_lds16(Bsrc0 + (k0), lBc + (buf) * 16384 + w * 1024);        \
        gload_lds16(Bsrc1 + (k0), lBc + (buf) * 16384 + 4096 + w * 1024); \
        gload_lds16(Bsrc2 + (k0), lBc + (buf) * 16384 + 8192 + w * 1024); \
        gload_lds16(Bsrc3 + (k0), lBc + (buf) * 16384 + 12288 + w * 1024);\
    } while (0)

    GE_STAGE(0, 0);
    __syncthreads();

    const int nIt = K >> 6;
    int cur = 0;
    for (int it = 0; it < nIt; ++it) {
        if (it + 1 < nIt) GE_STAGE(cur ^ 1, (it + 1) * 64);
#pragma unroll
        for (int ks = 0; ks < 2; ks++) {
            bf16x8 af[4], bfr[2];
#pragma unroll
            for (int i = 0; i < 4; i++) {
                const int row = i * 16 + l15;
                af[i] = *(const bf16x8*)(lAc + cur * 8192 + row * 128 +
                                         (((ks * 4 + l4) ^ (row & 7)) << 4));
            }
#pragma unroll
            for (int j = 0; j < 2; j++) {
                const int row = w * 32 + j * 16 + l15;
                bfr[j] = *(const bf16x8*)(lBc + cur * 16384 + row * 128 +
                                          (((ks * 4 + l4) ^ (row & 7)) << 4));
            }
#pragma unroll
            for (int i = 0; i < 4; i++)
#pragma unroll
                for (int j = 0; j < 2; j++)
                    acc[i][j] = __builtin_amdgcn_mfma_f32_16x16x32_bf16(af[i], bfr[j], acc[i][j], 0, 0, 0);
        }
        __syncthreads();
        cur ^= 1;
    }
#undef GE_STAGE

    const int mbase = bm * 64;
    const int nbase = bn * 128 + w * 32;
#pragma unroll
    for (int j = 0; j < 2; j++) {
        const int nf16 = nbase + j * 16;
        const float bv = bias[nf16 + l15];
        if constexpr (EPI == EPI_QKV) {
            const int head = nf16 / 192;
            const int rem = nf16 - head * 192;
            const int part = rem >> 6;
            const int dh = (rem & 63) + l15;
#pragma unroll
            for (int i = 0; i < 4; i++) {
                const int m0 = mbase + i * 16 + l4 * 4;
                const int b = m0 >> 11, s0 = m0 & 2047;
                if (part == 2) {
                    us4 pv;
#pragma unroll
                    for (int r = 0; r < 4; r++) pv[r] = f2b(acc[i][j][r] + bv);
                    *(us4*)(&Ov[((size_t)(b * 8 + head) * 64 + dh) * 2048 + s0]) = pv;
                } else if (part == 0) {
#pragma unroll
                    for (int r = 0; r < 4; r++)
                        Oq[((size_t)(b * 8 + head) * 2048 + s0 + r) * 64 + dh] =
                            f2b((acc[i][j][r] + bv) * qs);
                } else {
#pragma unroll
                    for (int r = 0; r < 4; r++)
                        Ok[((size_t)(b * 8 + head) * 2048 + s0 + r) * 64 + dh] =
                            f2b(acc[i][j][r] + bv);
                }
            }
        } else {
#pragma unroll
            for (int i = 0; i < 4; i++) {
                const int m0 = mbase + i * 16 + l4 * 4;
#pragma unroll
                for (int r = 0; r < 4; r++) {
                    const size_t idx = (size_t)(m0 + r) * N + nf16 + l15;
                    const float v = acc[i][j][r] + bv;
                    Cb[idx] = f2b(v > 0.f ? v : 0.f);
                }
            }
        }
    }
}

// ---------------- GEMM 64x128, split-K=2, writes bf16 partials --------------
__global__ __launch_bounds__(256, 2) void gemm64_splitk(
    const ushort_t* __restrict__ A, const ushort_t* __restrict__ Wt,
    ushort_t* __restrict__ P0, ushort_t* __restrict__ P1, int M, int N, int K)
{
    __shared__ __align__(16) ushort_t lA[2][64 * 64];
    __shared__ __align__(16) ushort_t lB[2][128 * 64];
    const int nbm = M >> 6;
    const int nbn = N >> 7;
    int bid = blockIdx.x;
    const int bm = bid % nbm; bid /= nbm;
    const int bn = bid % nbn;
    const int kh = bid / nbn;
    const int Keff = K >> 1;
    const int kbase = kh * Keff;
    const int tid = threadIdx.x, lane = tid & 63, w = tid >> 6;
    const int l15 = lane & 15, l4 = lane >> 4;

    f32x4 acc[4][2];
#pragma unroll
    for (int i = 0; i < 4; i++)
#pragma unroll
        for (int j = 0; j < 2; j++) { f32x4 z = {0.f, 0.f, 0.f, 0.f}; acc[i][j] = z; }

    const int srow = tid >> 3;
    const int sch = tid & 7;
    const int swch = sch ^ (srow & 7);
    const ushort_t* Asrc0 = A  + (size_t)(bm * 64 + srow) * K + kbase + swch * 8;
    const ushort_t* Asrc1 = A  + (size_t)(bm * 64 + srow + 32) * K + kbase + swch * 8;
    const ushort_t* Bsrc0 = Wt + (size_t)(bn * 128 + srow) * K + kbase + swch * 8;
    const ushort_t* Bsrc1 = Wt + (size_t)(bn * 128 + srow + 32) * K + kbase + swch * 8;
    const ushort_t* Bsrc2 = Wt + (size_t)(bn * 128 + srow + 64) * K + kbase + swch * 8;
    const ushort_t* Bsrc3 = Wt + (size_t)(bn * 128 + srow + 96) * K + kbase + swch * 8;
    char* lAc = (char*)lA;
    char* lBc = (char*)lB;

#define GE_STAGE(buf, k0) do {                                            \
        gload_lds16(Asrc0 + (k0), lAc + (buf) * 8192  + w * 1024);        \
        gload_lds16(Asrc1 + (k0), lAc + (buf) * 8192  + 4096 + w * 1024); \
        gload_lds16(Bsrc0 + (k0), lBc + (buf) * 16384 + w * 1024);        \
        gload_lds16(Bsrc1 + (k0), lBc + (buf) * 16384 + 4096 + w * 1024); \
        gload_lds16(Bsrc2 + (k0), lBc + (buf) * 16384 + 8192 + w * 1024); \
        gload_lds16(Bsrc3 + (k0), lBc + (buf) * 16384 + 12288 + w * 1024);\
    } while (0)

    GE_STAGE(0, 0);
    __syncthreads();

    const int nIt = Keff >> 6;
    int cur = 0;
    for (int it = 0; it < nIt; ++it) {
        if (it + 1 < nIt) GE_STAGE(cur ^ 1, (it + 1) * 64);
#pragma unroll
        for (int ks = 0; ks < 2; ks++) {
            bf16x8 af[4], bfr[2];
#pragma unroll
            for (int i = 0; i < 4; i++) {
                const int row = i * 16 + l15;
                af[i] = *(const bf16x8*)(lAc + cur * 8192 + row * 128 +
                                         (((ks * 4 + l4) ^ (row & 7)) << 4));
            }
#pragma unroll
            for (int j = 0; j < 2; j++) {
                const int row = w * 32 + j * 16 + l15;
                bfr[j] = *(const bf16x8*)(lBc + cur * 16384 + row * 128 +
                                          (((ks * 4 + l4) ^ (row & 7)) << 4));
            }
#pragma unroll
            for (int i = 0; i < 4; i++)
#pragma unroll
                for (int j = 0; j < 2; j++)
                    acc[i][j] = __builtin_amdgcn_mfma_f32_16x16x32_bf16(af[i], bfr[j], acc[i][j], 0, 0, 0);
        }
        __syncthreads();
        cur ^= 1;
    }
#undef GE_STAGE

    ushort_t* out = kh ? P1 : P0;
    const int mbase = bm * 64;
    const int nbase = bn * 128 + w * 32;
#pragma unroll
    for (int j = 0; j < 2; j++) {
        const int nf16 = nbase + j * 16;
#pragma unroll
        for (int i = 0; i < 4; i++) {
            const int m0 = mbase + i * 16 + l4 * 4;
#pragma unroll
            for (int r = 0; r < 4; r++)
                out[(size_t)(m0 + r) * N + nf16 + l15] = f2b(acc[i][j][r]);
        }
    }
}

// ---------------- flash attention v13: v10 1-qi body, full KV, no combine --
// 512 blocks = 32 qt x 16 bh (qt*64 covers all 2048 rows — grid decode FIXED).
// No max-tracking; Q pre-scaled by scale*log2(e). niter runtime (anti-unroll).
// Q,K: [16][2048][64] bf16 ; Vt: [16][64][2048] bf16 ; O: [4096][512] bf16
__global__ __launch_bounds__(256, 4) void flash_attn13(
    const ushort_t* __restrict__ Q, const ushort_t* __restrict__ Kg,
    const ushort_t* __restrict__ Vg, ushort_t* __restrict__ O, int niter)
{
    __shared__ __align__(16) ushort_t lK[2][64 * 64];   // 16 KB
    __shared__ __align__(16) ushort_t lV[2][64 * 64];   // 16 KB
    __shared__ __align__(16) ushort_t lP[4][16 * 64];   //  8 KB -> 40 KB

    // id bits: [bh_hi:1][qt:5][bh_lo:3] — 32 qt x 64 rows = 2048 (exact)
    const int id = blockIdx.x;
    const int rest = id >> 3;
    const int qt = rest & 31;
    const int bh = (id & 7) + ((rest >> 5) << 3);
    const int tid = threadIdx.x, lane = tid & 63, w = tid >> 6;
    const int l15 = lane & 15, l4 = lane >> 4;
    const int qrow0 = qt * 64 + w * 16;

    const ushort_t* Qb = Q + ((size_t)bh * 2048 + qrow0) * 64;
    bf16x8 qf[2];
#pragma unroll
    for (int ks = 0; ks < 2; ks++)
        qf[ks] = *(const bf16x8*)(Qb + l15 * 64 + ks * 32 + l4 * 8);

    const ushort_t* Kbase = Kg + (size_t)bh * 2048 * 64;
    const ushort_t* Vbase = Vg + (size_t)bh * 64 * 2048;

    const f32x4 FZ = { 0.f, 0.f, 0.f, 0.f };
    float l_run = 0.f;
    f32x4 oacc[4];
#pragma unroll
    for (int nd = 0; nd < 4; nd++) oacc[nd] = FZ;

    char* lKc = (char*)lK;
    char* lVc = (char*)lV;
    char* myP = (char*)(lP[w]);

    const int srow8 = lane >> 3;
    const int sch = lane & 7;

#define FA_STAGE(buf, kt) do {                                              \
        const int row0_ = w * 16 + srow8;                                   \
        const int sc0_ = sch ^ (row0_ & 7);                                 \
        gload_lds16(Kbase + (size_t)((kt) * 64 + row0_) * 64 + sc0_ * 8,    \
                    lKc + (buf) * 8192 + w * 2048);                         \
        gload_lds16(Vbase + (size_t)row0_ * 2048 + (kt) * 64 + sc0_ * 8,    \
                    lVc + (buf) * 8192 + w * 2048);                         \
        gload_lds16(Kbase + (size_t)((kt) * 64 + row0_ + 8) * 64 + sc0_ * 8,\
                    lKc + (buf) * 8192 + w * 2048 + 1024);                  \
        gload_lds16(Vbase + (size_t)(row0_ + 8) * 2048 + (kt) * 64 + sc0_ * 8,\
                    lVc + (buf) * 8192 + w * 2048 + 1024);                  \
    } while (0)

// v10 body verbatim (proven VGPR 52, spill-free).
#define FA_BODY(CUR, IT, LIM) do {                                          \
    if ((IT) < (LIM)) FA_STAGE((CUR) ^ 1, (IT) + 1);                        \
    f32x4 sc[4];                                                            \
    __builtin_amdgcn_s_setprio(1);                                          \
    _Pragma("unroll")                                                       \
    for (int nf = 0; nf < 4; nf++) {                                        \
        const int krow = nf * 16 + l15;                                     \
        const bf16x8 kf0 = *(const bf16x8*)(lKc + (CUR) * 8192 + krow * 128 + \
                                            ((l4 ^ (krow & 7)) << 4));      \
        const bf16x8 kf1 = *(const bf16x8*)(lKc + (CUR) * 8192 + krow * 128 + \
                                            (((4 + l4) ^ (krow & 7)) << 4)); \
        sc[nf] = __builtin_amdgcn_mfma_f32_16x16x32_bf16(kf0, qf[0], FZ, 0, 0, 0); \
        sc[nf] = __builtin_amdgcn_mfma_f32_16x16x32_bf16(kf1, qf[1], sc[nf], 0, 0, 0); \
    }                                                                       \
    __builtin_amdgcn_s_setprio(0);                                          \
    {                                                                       \
        float ps0 = 0.f, ps1 = 0.f;                                         \
        _Pragma("unroll")                                                   \
        for (int nf = 0; nf < 4; nf++) {                                    \
            const float p0 = exp2f(sc[nf][0]);                              \
            const float p1 = exp2f(sc[nf][1]);                              \
            const float p2 = exp2f(sc[nf][2]);                              \
            const float p3 = exp2f(sc[nf][3]);                              \
            sc[nf][0] = p0; sc[nf][1] = p1;                                 \
            sc[nf][2] = p2; sc[nf][3] = p3;                                 \
            ps0 += p0 + p2; ps1 += p1 + p3;                                 \
        }                                                                   \
        l_run += ps0 + ps1;                                                 \
    }                                                                       \
    const int hh0 = (l15 >> 3) & 1;                                         \
    {                                                                       \
        char* rp = myP + l15 * 128;                                         \
        const int swz = (l15 & 7) << 4;                                     \
        _Pragma("unroll")                                                   \
        for (int nf = 0; nf < 4; nf++) {                                    \
            const unsigned pw0 = cvt_pk_bf16(sc[nf][0], sc[nf][1]);         \
            const unsigned pw1 = cvt_pk_bf16(sc[nf][2], sc[nf][3]);         \
            const unsigned wA = hh0 ? pw1 : pw0;                            \
            const unsigned wB = hh0 ? pw0 : pw1;                            \
            const int cbase = nf * 32 + l4 * 8;                             \
            *(unsigned*)(rp + ((cbase + hh0 * 4) ^ swz)) = wA;              \
            *(unsigned*)(rp + ((cbase + (1 - hh0) * 4) ^ swz)) = wB;        \
        }                                                                   \
    }                                                                       \
    __asm__ volatile("" ::: "memory");                                     \
    bf16x8 pa[2];                                                           \
    _Pragma("unroll")                                                       \
    for (int ks = 0; ks < 2; ks++)                                          \
        pa[ks] = *(const bf16x8*)(myP + l15 * 128 +                         \
                                  ((ks * 64 + l4 * 16) ^ ((l15 & 7) << 4))); \
    __builtin_amdgcn_s_setprio(1);                                          \
    _Pragma("unroll")                                                       \
    for (int ks = 0; ks < 2; ks++)                                          \
        _Pragma("unroll")                                                   \
        for (int nd = 0; nd < 4; nd++) {                                    \
            const int vrow = nd * 16 + l15;                                 \
            const bf16x8 vf = *(const bf16x8*)(lVc + (CUR) * 8192 + vrow * 128 + \
                                               (((ks * 4 + l4) ^ (vrow & 7)) << 4)); \
            oacc[nd] = __builtin_amdgcn_mfma_f32_16x16x32_bf16(pa[ks], vf, oacc[nd], 0, 0, 0); \
        }                                                                   \
    __builtin_amdgcn_s_setprio(0);                                          \
    __syncthreads();                                                        \
} while (0)

    FA_STAGE(0, 0);
    __syncthreads();

    const int lim = niter * 2 - 1;
#pragma unroll 1
    for (int it2 = 0; it2 < niter; ++it2) {
        FA_BODY(0, it2 * 2, lim);
        FA_BODY(1, it2 * 2 + 1, lim);
    }
#undef FA_BODY
#undef FA_STAGE

    // epilogue: complete l, normalize, write O directly
    l_run += __shfl_xor(l_run, 16);
    l_run += __shfl_xor(l_run, 32);
    const int bq = bh >> 3, hh = bh & 7;
#pragma unroll
    for (int r = 0; r < 4; r++) {
        const float lv = __shfl(l_run, l4 * 4 + r);
        const float inv = 1.f / lv;
        const int s = qrow0 + l4 * 4 + r;
#pragma unroll
        for (int nd = 0; nd < 4; nd++)
            O[((size_t)(bq * 2048 + s)) * 512 + hh * 64 + nd * 16 + l15] =
                f2b(oacc[nd][r] * inv);
    }
}

// ------- fused: x' = xf + p0 + p1 + bias ; y = LN(x') (bf16 partials) ------
template<int CN>
__global__ __launch_bounds__(256) void ln_fused(
    const float* __restrict__ Xf, const ushort_t* __restrict__ P0,
    const ushort_t* __restrict__ P1, const float* __restrict__ bias,
    const float* __restrict__ g, const float* __restrict__ beta,
    float* __restrict__ XfOut, ushort_t* __restrict__ Yb, float* __restrict__ Yf)
{
    const int row = blockIdx.x * 4 + (threadIdx.x >> 6);
    const int lane = threadIdx.x & 63;
    const size_t base = (size_t)row * 512;
    float4 x0 = ((const float4*)(Xf + base))[lane];
    float4 x1 = ((const float4*)(Xf + base))[lane + 64];
    const us4 a0 = ((const us4*)(P0 + base))[lane];
    const us4 a1 = ((const us4*)(P0 + base))[lane + 64];
    const us4 c0 = ((const us4*)(P1 + base))[lane];
    const us4 c1 = ((const us4*)(P1 + base))[lane + 64];
    const float4 bb0 = ((const float4*)bias)[lane];
    const float4 bb1 = ((const float4*)bias)[lane + 64];
    x0.x += b2f(a0[0]) + b2f(c0[0]) + bb0.x; x0.y += b2f(a0[1]) + b2f(c0[1]) + bb0.y;
    x0.z += b2f(a0[2]) + b2f(c0[2]) + bb0.z; x0.w += b2f(a0[3]) + b2f(c0[3]) + bb0.w;
    x1.x += b2f(a1[0]) + b2f(c1[0]) + bb1.x; x1.y += b2f(a1[1]) + b2f(c1[1]) + bb1.y;
    x1.z += b2f(a1[2]) + b2f(c1[2]) + bb1.z; x1.w += b2f(a1[3]) + b2f(c1[3]) + bb1.w;

    float s = x0.x + x0.y + x0.z + x0.w + x1.x + x1.y + x1.z + x1.w;
    float s2 = x0.x * x0.x + x0.y * x0.y + x0.z * x0.z + x0.w * x0.w
             + x1.x * x1.x + x1.y * x1.y + x1.z * x1.z + x1.w * x1.w;
#pragma unroll
    for (int m = 1; m < 64; m <<= 1) { s += __shfl_xor(s, m); s2 += __shfl_xor(s2, m); }
    const float mean = s * (1.f / 512.f);
    const float inv = rsqrtf(s2 * (1.f / 512.f) - mean * mean + 1e-5f);
    const float4 g0 = ((const float4*)g)[lane], g1 = ((const float4*)g)[lane + 64];
    const float4 b0 = ((const float4*)beta)[lane], b1 = ((const float4*)beta)[lane + 64];
    float4 y0, y1;
    y0.x = (x0.x - mean) * inv * g0.x + b0.x;
    y0.y = (x0.y - mean) * inv * g0.y + b0.y;
    y0.z = (x0.z - mean) * inv * g0.z + b0.z;
    y0.w = (x0.w - mean) * inv * g0.w + b0.w;
    y1.x = (x1.x - mean) * inv * g1.x + b1.x;
    y1.y = (x1.y - mean) * inv * g1.y + b1.y;
    y1.z = (x1.z - mean) * inv * g1.z + b1.z;
    y1.w = (x1.w - mean) * inv * g1.w + b1.w;
    if constexpr (CN == 0) {
        ((float4*)(XfOut + base))[lane] = x0;
        ((float4*)(XfOut + base))[lane + 64] = x1;
    } else {
        ((float4*)(XfOut + base))[lane] = y0;
        ((float4*)(XfOut + base))[lane + 64] = y1;
        if (Yf) {
            ((float4*)(Yf + base))[lane] = y0;
            ((float4*)(Yf + base))[lane + 64] = y1;
        }
    }
    us4 o0 = { f2b(y0.x), f2b(y0.y), f2b(y0.z), f2b(y0.w) };
    us4 o1 = { f2b(y1.x), f2b(y1.y), f2b(y1.z), f2b(y1.w) };
    ((us4*)(Yb + base))[lane] = o0;
    ((us4*)(Yb + base))[lane + 64] = o1;
}

// ---------------- host ----------------
extern "C" void kernel_launch(void* const* d_in, const int* in_sizes, int n_in,
                              void* d_out, int out_size, void* d_ws, size_t ws_size,
                              hipStream_t stream)
{
    (void)in_sizes; (void)n_in; (void)out_size; (void)ws_size;
    const float* X     = (const float*)d_in[0];
    const float* qkv_w = (const float*)d_in[1];
    const float* qkv_b = (const float*)d_in[2];
    const float* fc_w  = (const float*)d_in[3];
    const float* fc_b  = (const float*)d_in[4];
    const float* ln1_g = (const float*)d_in[5];
    const float* ln1_b = (const float*)d_in[6];
    const float* w1    = (const float*)d_in[7];
    const float* b1    = (const float*)d_in[8];
    const float* w2    = (const float*)d_in[9];
    const float* b2    = (const float*)d_in[10];
    const float* ln2_g = (const float*)d_in[11];
    const float* ln2_b = (const float*)d_in[12];

    char* ws = (char*)d_ws;
    size_t off = 0;
    auto alloc = [&](size_t bytes) -> char* {
        char* p = ws + off;
        off += (bytes + 255) & ~(size_t)255;
        return p;
    };
    ushort_t* qkvw_t = (ushort_t*)alloc(12ull * 1536 * 512 * 2);
    ushort_t* fcw_t  = (ushort_t*)alloc(12ull * 512 * 512 * 2);
    ushort_t* w1_t   = (ushort_t*)alloc(12ull * 512 * 1024 * 2);
    ushort_t* w2_t   = (ushort_t*)alloc(12ull * 1024 * 512 * 2);
    float*    xf     = (float*)   alloc(4096ull * 512 * 4);
    ushort_t* xb     = (ushort_t*)alloc(4096ull * 512 * 2);
    ushort_t* qb     = (ushort_t*)alloc(16ull * 2048 * 64 * 2);   // 4 MB
    ushort_t* kb     = (ushort_t*)alloc(16ull * 2048 * 64 * 2);   // 4 MB
    ushort_t* vt     = (ushort_t*)alloc(16ull * 64 * 2048 * 2);
    ushort_t* ob     = (ushort_t*)alloc(4096ull * 512 * 2);
    ushort_t* y1     = (ushort_t*)alloc(4096ull * 512 * 2);
    ushort_t* hbuf   = (ushort_t*)alloc(4096ull * 1024 * 2);
    // split-K bf16 partials alias qb/kb (dead between flash-consume and next QKV)
    ushort_t* pk0 = qb;
    ushort_t* pk1 = kb;

    transpose_cvt<<<dim3(48, 16, 12), 256, 0, stream>>>(qkv_w, qkvw_t, 512, 1536);
    transpose_cvt<<<dim3(16, 16, 12), 256, 0, stream>>>(fc_w, fcw_t, 512, 512);
    transpose_cvt<<<dim3(32, 16, 12), 256, 0, stream>>>(w1, w1_t, 512, 1024);
    transpose_cvt<<<dim3(16, 32, 12), 256, 0, stream>>>(w2, w2_t, 1024, 512);
    init_x<<<2048, 256, 0, stream>>>(X, xf, xb);

    const float sl2 = (float)(0.044194173824159216 * 1.4426950408889634); // scale*log2(e)
    for (int nb = 0; nb < 12; nb++) {
        gemm64<EPI_QKV><<<64 * 12, 256, 0, stream>>>(
            xb, qkvw_t + (size_t)nb * 1536 * 512, qkv_b + nb * 1536,
            nullptr, qb, kb, vt, 4096, 1536, 512, sl2);
        flash_attn13<<<512, 256, 0, stream>>>(qb, kb, vt, ob, 16);
        gemm64_splitk<<<64 * 4 * 2, 256, 0, stream>>>(
            ob, fcw_t + (size_t)nb * 512 * 512, pk0, pk1, 4096, 512, 512);
        ln_fused<0><<<1024, 256, 0, stream>>>(
            xf, pk0, pk1, fc_b + nb * 512, ln1_g + nb * 512, ln1_b + nb * 512,
            xf, y1, nullptr);
        gemm64<EPI_RELUB><<<64 * 8, 256, 0, stream>>>(
            y1, w1_t + (size_t)nb * 1024 * 512, b1 + nb * 1024,
            hbuf, nullptr, nullptr, nullptr, 4096, 1024, 512, 1.f);
        gemm64_splitk<<<64 * 4 * 2, 256, 0, stream>>>(
            hbuf, w2_t + (size_t)nb * 1024 * 512, pk0, pk1, 4096, 512, 1024);
        ln_fused<1><<<1024, 256, 0, stream>>>(
            xf, pk0, pk1, b2 + nb * 512, ln2_g + nb * 512, ln2_b + nb * 512,
            xf, xb, nb == 11 ? (float*)d_out : nullptr);
    }
}

// Round 14
// 1151.370 us; speedup vs baseline: 1.2524x; 1.0005x over previous
//
#include <hip/hip_runtime.h>

typedef unsigned short ushort_t;
typedef __attribute__((ext_vector_type(8))) short bf16x8;
typedef __attribute__((ext_vector_type(4))) float f32x4;
typedef __attribute__((ext_vector_type(4))) unsigned short us4;

#define DEV __device__ __forceinline__

DEV ushort_t f2b(float f) {
    union { float f; unsigned u; } x; x.f = f;
    unsigned r = (x.u + 0x7fffu + ((x.u >> 16) & 1u)) >> 16;
    return (ushort_t)r;
}

DEV float b2f(ushort_t u) {
    union { unsigned u; float f; } x; x.u = ((unsigned)u) << 16;
    return x.f;
}

DEV unsigned cvt_pk_bf16(float lo, float hi) {
    unsigned r;
    asm("v_cvt_pk_bf16_f32 %0, %1, %2" : "=v"(r) : "v"(lo), "v"(hi));
    return r;
}

typedef void __attribute__((address_space(1)))* gp1;
typedef void __attribute__((address_space(3)))* sp3;
DEV void gload_lds16(const void* g, void* l) {
    __builtin_amdgcn_global_load_lds((gp1)g, (sp3)l, 16, 0, 0);
}

// ---------------- weight prep: f32 [K][N] -> bf16 [N][K] ----------------
__global__ __launch_bounds__(256) void transpose_cvt(
    const float* __restrict__ in, ushort_t* __restrict__ out, int K, int N)
{
    __shared__ float tile[32][33];
    const int nb = blockIdx.z;
    const float* src = in + (size_t)nb * K * N;
    ushort_t* dst = out + (size_t)nb * K * N;
    const int n0 = blockIdx.x * 32, k0 = blockIdx.y * 32;
    const int tx = threadIdx.x & 31, ty = threadIdx.x >> 5;
#pragma unroll
    for (int i = 0; i < 32; i += 8)
        tile[ty + i][tx] = src[(size_t)(k0 + ty + i) * N + n0 + tx];
    __syncthreads();
#pragma unroll
    for (int i = 0; i < 32; i += 8)
        dst[(size_t)(n0 + ty + i) * K + k0 + tx] = f2b(tile[tx][ty + i]);
}

// ---------------- init: X f32 -> xf f32 copy + xb bf16 ----------------
__global__ __launch_bounds__(256) void init_x(
    const float* __restrict__ X, float* __restrict__ xf, ushort_t* __restrict__ xb)
{
    const int i = blockIdx.x * 256 + threadIdx.x;
    const float4 v = ((const float4*)X)[i];
    ((float4*)xf)[i] = v;
    us4 o = { f2b(v.x), f2b(v.y), f2b(v.z), f2b(v.w) };
    ((us4*)xb)[i] = o;
}

enum { EPI_QKV = 0, EPI_RELUB = 2 };

// ---------------- GEMM 128x128 tile, BK=64 (QKV) — round-5 proven ----------
__global__ __launch_bounds__(256, 2) void gemm128_qkv(
    const ushort_t* __restrict__ A, const ushort_t* __restrict__ Wt,
    const float* __restrict__ bias,
    ushort_t* __restrict__ Oq, ushort_t* __restrict__ Ok, ushort_t* __restrict__ Ov,
    int M, int N, int K, float qs)
{
    __shared__ __align__(16) ushort_t lA[2][128 * 64];
    __shared__ __align__(16) ushort_t lB[2][128 * 64];
    const int nbm = M >> 7;
    const int bm = blockIdx.x % nbm;
    const int bn = blockIdx.x / nbm;
    const int tid = threadIdx.x, lane = tid & 63, w = tid >> 6;
    const int wr = w >> 1, wc = w & 1;
    const int l15 = lane & 15, l4 = lane >> 4;

    f32x4 acc[4][4];
#pragma unroll
    for (int i = 0; i < 4; i++)
#pragma unroll
        for (int j = 0; j < 4; j++) { f32x4 z = {0.f, 0.f, 0.f, 0.f}; acc[i][j] = z; }

    const int srow = tid >> 3;           // 0..31
    const int sch = tid & 7;
    const int swch = sch ^ (srow & 7);   // +32k keeps row&7
    const ushort_t* As[4];
    const ushort_t* Bs[4];
#pragma unroll
    for (int i = 0; i < 4; i++) {
        As[i] = A  + (size_t)(bm * 128 + srow + i * 32) * K + swch * 8;
        Bs[i] = Wt + (size_t)(bn * 128 + srow + i * 32) * K + swch * 8;
    }
    char* lAc = (char*)lA;
    char* lBc = (char*)lB;

#define GE_STAGE(buf, k0) do {                                              \
        _Pragma("unroll")                                                   \
        for (int i_ = 0; i_ < 4; i_++) {                                    \
            gload_lds16(As[i_] + (k0), lAc + (buf) * 16384 + i_ * 4096 + w * 1024); \
            gload_lds16(Bs[i_] + (k0), lBc + (buf) * 16384 + i_ * 4096 + w * 1024); \
        } } while (0)

    GE_STAGE(0, 0);
    __syncthreads();

    const int nIt = K >> 6;
    int cur = 0;
    for (int it = 0; it < nIt; ++it) {
        if (it + 1 < nIt) GE_STAGE(cur ^ 1, (it + 1) * 64);
#pragma unroll
        for (int ks = 0; ks < 2; ks++) {
            bf16x8 af[4], bfr[4];
#pragma unroll
            for (int i = 0; i < 4; i++) {
                const int rowa = wr * 64 + i * 16 + l15;
                af[i] = *(const bf16x8*)(lAc + cur * 16384 + rowa * 128 +
                                         (((ks * 4 + l4) ^ (rowa & 7)) << 4));
                const int rowb = wc * 64 + i * 16 + l15;
                bfr[i] = *(const bf16x8*)(lBc + cur * 16384 + rowb * 128 +
                                          (((ks * 4 + l4) ^ (rowb & 7)) << 4));
            }
#pragma unroll
            for (int i = 0; i < 4; i++)
#pragma unroll
                for (int j = 0; j < 4; j++)
                    acc[i][j] = __builtin_amdgcn_mfma_f32_16x16x32_bf16(af[i], bfr[j], acc[i][j], 0, 0, 0);
        }
        __syncthreads();
        cur ^= 1;
    }
#undef GE_STAGE

    const int mbase = bm * 128 + wr * 64;
    const int nbase = bn * 128 + wc * 64;
#pragma unroll
    for (int j = 0; j < 4; j++) {
        const int nf16 = nbase + j * 16;
        const float bv = bias[nf16 + l15];
        const int head = nf16 / 192;
        const int rem = nf16 - head * 192;
        const int part = rem >> 6;
        const int dh = (rem & 63) + l15;
#pragma unroll
        for (int i = 0; i < 4; i++) {
            const int m0 = mbase + i * 16 + l4 * 4;
            const int b = m0 >> 11, s0 = m0 & 2047;
            if (part == 2) {
                us4 pv;
#pragma unroll
                for (int r = 0; r < 4; r++) pv[r] = f2b(acc[i][j][r] + bv);
                *(us4*)(&Ov[((size_t)(b * 8 + head) * 64 + dh) * 2048 + s0]) = pv;
            } else if (part == 0) {
#pragma unroll
                for (int r = 0; r < 4; r++)
                    Oq[((size_t)(b * 8 + head) * 2048 + s0 + r) * 64 + dh] =
                        f2b((acc[i][j][r] + bv) * qs);
            } else {
#pragma unroll
                for (int r = 0; r < 4; r++)
                    Ok[((size_t)(b * 8 + head) * 2048 + s0 + r) * 64 + dh] =
                        f2b(acc[i][j][r] + bv);
            }
        }
    }
}

// ---------------- GEMM 64x128 tile, BK=64 (MLP1) ---------------------------
template<int EPI>
__global__ __launch_bounds__(256, 2) void gemm64(
    const ushort_t* __restrict__ A, const ushort_t* __restrict__ Wt,
    const float* __restrict__ bias, ushort_t* __restrict__ Cb,
    int M, int N, int K)
{
    __shared__ __align__(16) ushort_t lA[2][64 * 64];
    __shared__ __align__(16) ushort_t lB[2][128 * 64];
    const int nbm = M >> 6;
    const int bm = blockIdx.x % nbm;
    const int bn = blockIdx.x / nbm;
    const int tid = threadIdx.x, lane = tid & 63, w = tid >> 6;
    const int l15 = lane & 15, l4 = lane >> 4;

    f32x4 acc[4][2];
#pragma unroll
    for (int i = 0; i < 4; i++)
#pragma unroll
        for (int j = 0; j < 2; j++) { f32x4 z = {0.f, 0.f, 0.f, 0.f}; acc[i][j] = z; }

    const int srow = tid >> 3;
    const int sch = tid & 7;
    const int swch = sch ^ (srow & 7);
    const ushort_t* Asrc0 = A  + (size_t)(bm * 64 + srow) * K + swch * 8;
    const ushort_t* Asrc1 = A  + (size_t)(bm * 64 + srow + 32) * K + swch * 8;
    const ushort_t* Bsrc0 = Wt + (size_t)(bn * 128 + srow) * K + swch * 8;
    const ushort_t* Bsrc1 = Wt + (size_t)(bn * 128 + srow + 32) * K + swch * 8;
    const ushort_t* Bsrc2 = Wt + (size_t)(bn * 128 + srow + 64) * K + swch * 8;
    const ushort_t* Bsrc3 = Wt + (size_t)(bn * 128 + srow + 96) * K + swch * 8;
    char* lAc = (char*)lA;
    char* lBc = (char*)lB;

#define GE_STAGE(buf, k0) do {                                            \
        gload_lds16(Asrc0 + (k0), lAc + (buf) * 8192  + w * 1024);        \
        gload_lds16(Asrc1 + (k0), lAc + (buf) * 8192  + 4096 + w * 1024); \
        gload_lds16(Bsrc0 + (k0), lBc + (buf) * 16384 + w * 1024);        \
        gload_lds16(Bsrc1 + (k0), lBc + (buf) * 16384 + 4096 + w * 1024); \
        gload_lds16(Bsrc2 + (k0), lBc + (buf) * 16384 + 8192 + w * 1024); \
        gload_lds16(Bsrc3 + (k0), lBc + (buf) * 16384 + 12288 + w * 1024);\
    } while (0)

    GE_STAGE(0, 0);
    __syncthreads();

    const int nIt = K >> 6;
    int cur = 0;
    for (int it = 0; it < nIt; ++it) {
        if (it + 1 < nIt) GE_STAGE(cur ^ 1, (it + 1) * 64);
#pragma unroll
        for (int ks = 0; ks < 2; ks++) {
            bf16x8 af[4], bfr[2];
#pragma unroll
            for (int i = 0; i < 4; i++) {
                const int row = i * 16 + l15;
                af[i] = *(const bf16x8*)(lAc + cur * 8192 + row * 128 +
                                         (((ks * 4 + l4) ^ (row & 7)) << 4));
            }
#pragma unroll
            for (int j = 0; j < 2; j++) {
                const int row = w * 32 + j * 16 + l15;
                bfr[j] = *(const bf16x8*)(lBc + cur * 16384 + row * 128 +
                                          (((ks * 4 + l4) ^ (row & 7)) << 4));
            }
#pragma unroll
            for (int i = 0; i < 4; i++)
#pragma unroll
                for (int j = 0; j < 2; j++)
                    acc[i][j] = __builtin_amdgcn_mfma_f32_16x16x32_bf16(af[i], bfr[j], acc[i][j], 0, 0, 0);
        }
        __syncthreads();
        cur ^= 1;
    }
#undef GE_STAGE

    const int mbase = bm * 64;
    const int nbase = bn * 128 + w * 32;
#pragma unroll
    for (int j = 0; j < 2; j++) {
        const int nf16 = nbase + j * 16;
        const float bv = bias[nf16 + l15];
#pragma unroll
        for (int i = 0; i < 4; i++) {
            const int m0 = mbase + i * 16 + l4 * 4;
#pragma unroll
            for (int r = 0; r < 4; r++) {
                const size_t idx = (size_t)(m0 + r) * N + nf16 + l15;
                const float v = acc[i][j][r] + bv;
                Cb[idx] = f2b(v > 0.f ? v : 0.f);
            }
        }
    }
}

// ---------------- GEMM 64x128, split-K=2, writes bf16 partials --------------
__global__ __launch_bounds__(256, 2) void gemm64_splitk(
    const ushort_t* __restrict__ A, const ushort_t* __restrict__ Wt,
    ushort_t* __restrict__ P0, ushort_t* __restrict__ P1, int M, int N, int K)
{
    __shared__ __align__(16) ushort_t lA[2][64 * 64];
    __shared__ __align__(16) ushort_t lB[2][128 * 64];
    const int nbm = M >> 6;
    const int nbn = N >> 7;
    int bid = blockIdx.x;
    const int bm = bid % nbm; bid /= nbm;
    const int bn = bid % nbn;
    const int kh = bid / nbn;
    const int Keff = K >> 1;
    const int kbase = kh * Keff;
    const int tid = threadIdx.x, lane = tid & 63, w = tid >> 6;
    const int l15 = lane & 15, l4 = lane >> 4;

    f32x4 acc[4][2];
#pragma unroll
    for (int i = 0; i < 4; i++)
#pragma unroll
        for (int j = 0; j < 2; j++) { f32x4 z = {0.f, 0.f, 0.f, 0.f}; acc[i][j] = z; }

    const int srow = tid >> 3;
    const int sch = tid & 7;
    const int swch = sch ^ (srow & 7);
    const ushort_t* Asrc0 = A  + (size_t)(bm * 64 + srow) * K + kbase + swch * 8;
    const ushort_t* Asrc1 = A  + (size_t)(bm * 64 + srow + 32) * K + kbase + swch * 8;
    const ushort_t* Bsrc0 = Wt + (size_t)(bn * 128 + srow) * K + kbase + swch * 8;
    const ushort_t* Bsrc1 = Wt + (size_t)(bn * 128 + srow + 32) * K + kbase + swch * 8;
    const ushort_t* Bsrc2 = Wt + (size_t)(bn * 128 + srow + 64) * K + kbase + swch * 8;
    const ushort_t* Bsrc3 = Wt + (size_t)(bn * 128 + srow + 96) * K + kbase + swch * 8;
    char* lAc = (char*)lA;
    char* lBc = (char*)lB;

#define GE_STAGE(buf, k0) do {                                            \
        gload_lds16(Asrc0 + (k0), lAc + (buf) * 8192  + w * 1024);        \
        gload_lds16(Asrc1 + (k0), lAc + (buf) * 8192  + 4096 + w * 1024); \
        gload_lds16(Bsrc0 + (k0), lBc + (buf) * 16384 + w * 1024);        \
        gload_lds16(Bsrc1 + (k0), lBc + (buf) * 16384 + 4096 + w * 1024); \
        gload_lds16(Bsrc2 + (k0), lBc + (buf) * 16384 + 8192 + w * 1024); \
        gload_lds16(Bsrc3 + (k0), lBc + (buf) * 16384 + 12288 + w * 1024);\
    } while (0)

    GE_STAGE(0, 0);
    __syncthreads();

    const int nIt = Keff >> 6;
    int cur = 0;
    for (int it = 0; it < nIt; ++it) {
        if (it + 1 < nIt) GE_STAGE(cur ^ 1, (it + 1) * 64);
#pragma unroll
        for (int ks = 0; ks < 2; ks++) {
            bf16x8 af[4], bfr[2];
#pragma unroll
            for (int i = 0; i < 4; i++) {
                const int row = i * 16 + l15;
                af[i] = *(const bf16x8*)(lAc + cur * 8192 + row * 128 +
                                         (((ks * 4 + l4) ^ (row & 7)) << 4));
            }
#pragma unroll
            for (int j = 0; j < 2; j++) {
                const int row = w * 32 + j * 16 + l15;
                bfr[j] = *(const bf16x8*)(lBc + cur * 16384 + row * 128 +
                                          (((ks * 4 + l4) ^ (row & 7)) << 4));
            }
#pragma unroll
            for (int i = 0; i < 4; i++)
#pragma unroll
                for (int j = 0; j < 2; j++)
                    acc[i][j] = __builtin_amdgcn_mfma_f32_16x16x32_bf16(af[i], bfr[j], acc[i][j], 0, 0, 0);
        }
        __syncthreads();
        cur ^= 1;
    }
#undef GE_STAGE

    ushort_t* out = kh ? P1 : P0;
    const int mbase = bm * 64;
    const int nbase = bn * 128 + w * 32;
#pragma unroll
    for (int j = 0; j < 2; j++) {
        const int nf16 = nbase + j * 16;
#pragma unroll
        for (int i = 0; i < 4; i++) {
            const int m0 = mbase + i * 16 + l4 * 4;
#pragma unroll
            for (int r = 0; r < 4; r++)
                out[(size_t)(m0 + r) * N + nf16 + l15] = f2b(acc[i][j][r]);
        }
    }
}

// ---------------- flash attention v11 (round-11 best): 2-qi, KV-split 4 ----
__global__ __launch_bounds__(256, 4) void flash_attn11(
    const ushort_t* __restrict__ Q, const ushort_t* __restrict__ Kg,
    const ushort_t* __restrict__ Vg, ushort_t* __restrict__ Opart,
    float* __restrict__ lbuf, int niter)
{
    __shared__ __align__(16) ushort_t lK[2][64 * 64];
    __shared__ __align__(16) ushort_t lV[2][64 * 64];
    __shared__ __align__(16) ushort_t lP[4][16 * 64];

    const int id = blockIdx.x;
    const int rest = id >> 3;
    const int kvh = rest & 3;
    const int qt = (rest >> 2) & 15;
    const int bh = (id & 7) + ((rest >> 6) << 3);
    const int tid = threadIdx.x, lane = tid & 63, w = tid >> 6;
    const int l15 = lane & 15, l4 = lane >> 4;
    const int qrow0 = qt * 128 + w * 32;

    const ushort_t* Qb = Q + ((size_t)bh * 2048 + qrow0) * 64;
    bf16x8 qf[2][2];
#pragma unroll
    for (int qi = 0; qi < 2; qi++)
#pragma unroll
        for (int ks = 0; ks < 2; ks++)
            qf[qi][ks] = *(const bf16x8*)(Qb + (qi * 16 + l15) * 64 + ks * 32 + l4 * 8);

    const ushort_t* Kbase = Kg + (size_t)bh * 2048 * 64;
    const ushort_t* Vbase = Vg + (size_t)bh * 64 * 2048;

    const f32x4 FZ = { 0.f, 0.f, 0.f, 0.f };
    float l_run[2] = { 0.f, 0.f };
    f32x4 oacc[2][4];
#pragma unroll
    for (int qi = 0; qi < 2; qi++)
#pragma unroll
        for (int nd = 0; nd < 4; nd++) oacc[qi][nd] = FZ;

    char* lKc = (char*)lK;
    char* lVc = (char*)lV;
    char* myP = (char*)(lP[w]);

    const int srow8 = lane >> 3;
    const int sch = lane & 7;

#define FA_STAGE(buf, kt) do {                                              \
        const int row0_ = w * 16 + srow8;                                   \
        const int sc0_ = sch ^ (row0_ & 7);                                 \
        gload_lds16(Kbase + (size_t)((kt) * 64 + row0_) * 64 + sc0_ * 8,    \
                    lKc + (buf) * 8192 + w * 2048);                         \
        gload_lds16(Vbase + (size_t)row0_ * 2048 + (kt) * 64 + sc0_ * 8,    \
                    lVc + (buf) * 8192 + w * 2048);                         \
        gload_lds16(Kbase + (size_t)((kt) * 64 + row0_ + 8) * 64 + sc0_ * 8,\
                    lKc + (buf) * 8192 + w * 2048 + 1024);                  \
        gload_lds16(Vbase + (size_t)(row0_ + 8) * 2048 + (kt) * 64 + sc0_ * 8,\
                    lVc + (buf) * 8192 + w * 2048 + 1024);                  \
    } while (0)

#define FA_BODY(CUR, IT, LIM) do {                                          \
    if ((IT) < (LIM)) FA_STAGE((CUR) ^ 1, kt0 + (IT) + 1);                  \
    f32x4 sc[2][4];                                                         \
    __builtin_amdgcn_s_setprio(1);                                          \
    _Pragma("unroll")                                                       \
    for (int nf = 0; nf < 4; nf++) {                                        \
        const int krow = nf * 16 + l15;                                     \
        const bf16x8 kf0 = *(const bf16x8*)(lKc + (CUR) * 8192 + krow * 128 + \
                                            ((l4 ^ (krow & 7)) << 4));      \
        const bf16x8 kf1 = *(const bf16x8*)(lKc + (CUR) * 8192 + krow * 128 + \
                                            (((4 + l4) ^ (krow & 7)) << 4)); \
        sc[0][nf] = __builtin_amdgcn_mfma_f32_16x16x32_bf16(kf0, qf[0][0], FZ, 0, 0, 0); \
        sc[1][nf] = __builtin_amdgcn_mfma_f32_16x16x32_bf16(kf0, qf[1][0], FZ, 0, 0, 0); \
        sc[0][nf] = __builtin_amdgcn_mfma_f32_16x16x32_bf16(kf1, qf[0][1], sc[0][nf], 0, 0, 0); \
        sc[1][nf] = __builtin_amdgcn_mfma_f32_16x16x32_bf16(kf1, qf[1][1], sc[1][nf], 0, 0, 0); \
    }                                                                       \
    __builtin_amdgcn_s_setprio(0);                                          \
    _Pragma("unroll")                                                       \
    for (int qi = 0; qi < 2; qi++) {                                        \
        float ps0 = 0.f, ps1 = 0.f;                                         \
        _Pragma("unroll")                                                   \
        for (int nf = 0; nf < 4; nf++) {                                    \
            const float p0 = exp2f(sc[qi][nf][0]);                          \
            const float p1 = exp2f(sc[qi][nf][1]);                          \
            const float p2 = exp2f(sc[qi][nf][2]);                          \
            const float p3 = exp2f(sc[qi][nf][3]);                          \
            sc[qi][nf][0] = p0; sc[qi][nf][1] = p1;                         \
            sc[qi][nf][2] = p2; sc[qi][nf][3] = p3;                         \
            ps0 += p0 + p2; ps1 += p1 + p3;                                 \
        }                                                                   \
        l_run[qi] += ps0 + ps1;                                             \
    }                                                                       \
    const int hh0 = (l15 >> 3) & 1;                                         \
    char* rp = myP + l15 * 128;                                             \
    const int swz = (l15 & 7) << 4;                                         \
    bf16x8 pa[2][2];                                                        \
    _Pragma("unroll")                                                       \
    for (int nf = 0; nf < 4; nf++) {                                        \
        const unsigned pw0 = cvt_pk_bf16(sc[0][nf][0], sc[0][nf][1]);       \
        const unsigned pw1 = cvt_pk_bf16(sc[0][nf][2], sc[0][nf][3]);       \
        const unsigned wA = hh0 ? pw1 : pw0;                                \
        const unsigned wB = hh0 ? pw0 : pw1;                                \
        const int cbase = nf * 32 + l4 * 8;                                 \
        *(unsigned*)(rp + ((cbase + hh0 * 4) ^ swz)) = wA;                  \
        *(unsigned*)(rp + ((cbase + (1 - hh0) * 4) ^ swz)) = wB;            \
    }                                                                       \
    __asm__ volatile("" ::: "memory");                                     \
    pa[0][0] = *(const bf16x8*)(myP + l15 * 128 + ((l4 * 16) ^ swz));       \
    pa[0][1] = *(const bf16x8*)(myP + l15 * 128 + ((64 + l4 * 16) ^ swz));  \
    __asm__ volatile("" ::: "memory");                                     \
    _Pragma("unroll")                                                       \
    for (int nf = 0; nf < 4; nf++) {                                        \
        const unsigned pw0 = cvt_pk_bf16(sc[1][nf][0], sc[1][nf][1]);       \
        const unsigned pw1 = cvt_pk_bf16(sc[1][nf][2], sc[1][nf][3]);       \
        const unsigned wA = hh0 ? pw1 : pw0;                                \
        const unsigned wB = hh0 ? pw0 : pw1;                                \
        const int cbase = nf * 32 + l4 * 8;                                 \
        *(unsigned*)(rp + ((cbase + hh0 * 4) ^ swz)) = wA;                  \
        *(unsigned*)(rp + ((cbase + (1 - hh0) * 4) ^ swz)) = wB;            \
    }                                                                       \
    __asm__ volatile("" ::: "memory");                                     \
    pa[1][0] = *(const bf16x8*)(myP + l15 * 128 + ((l4 * 16) ^ swz));       \
    pa[1][1] = *(const bf16x8*)(myP + l15 * 128 + ((64 + l4 * 16) ^ swz));  \
    __asm__ volatile("" ::: "memory");                                     \
    __builtin_amdgcn_s_setprio(1);                                          \
    _Pragma("unroll")                                                       \
    for (int ks = 0; ks < 2; ks++)                                          \
        _Pragma("unroll")                                                   \
        for (int nd = 0; nd < 4; nd++) {                                    \
            const int vrow = nd * 16 + l15;                                 \
            const bf16x8 vf = *(const bf16x8*)(lVc + (CUR) * 8192 + vrow * 128 + \
                                               (((ks * 4 + l4) ^ (vrow & 7)) << 4)); \
            oacc[0][nd] = __builtin_amdgcn_mfma_f32_16x16x32_bf16(pa[0][ks], vf, oacc[0][nd], 0, 0, 0); \
            oacc[1][nd] = __builtin_amdgcn_mfma_f32_16x16x32_bf16(pa[1][ks], vf, oacc[1][nd], 0, 0, 0); \
        }                                                                   \
    __builtin_amdgcn_s_setprio(0);                                          \
    __syncthreads();                                                        \
} while (0)

    const int kt0 = kvh * 8;
    FA_STAGE(0, kt0);
    __syncthreads();

    const int lim = niter * 2 - 1;
#pragma unroll 1
    for (int it2 = 0; it2 < niter; ++it2) {
        FA_BODY(0, it2 * 2, lim);
        FA_BODY(1, it2 * 2 + 1, lim);
    }
#undef FA_BODY
#undef FA_STAGE

#pragma unroll
    for (int qi = 0; qi < 2; qi++) {
        l_run[qi] += __shfl_xor(l_run[qi], 16);
        l_run[qi] += __shfl_xor(l_run[qi], 32);
    }
    ushort_t* Op = Opart + ((size_t)(kvh * 16 + bh) * 2048 + qrow0) * 64;
#pragma unroll
    for (int qi = 0; qi < 2; qi++)
#pragma unroll
        for (int r = 0; r < 4; r++)
#pragma unroll
            for (int nd = 0; nd < 4; nd++)
                Op[(size_t)(qi * 16 + l4 * 4 + r) * 64 + nd * 16 + l15] =
                    f2b(oacc[qi][nd][r]);
    if (lane < 32) {
        const int qi = lane >> 4;
        lbuf[(size_t)(kvh * 16 + bh) * 2048 + qrow0 + qi * 16 + (lane & 15)] =
            qi ? l_run[1] : l_run[0];
    }
}

// ---------------- combine the four KV quarters (l-weighted sum) -------------
__global__ __launch_bounds__(256) void combine_attn(
    const ushort_t* __restrict__ Opart, const float* __restrict__ lbuf,
    ushort_t* __restrict__ O)
{
    const int gid = blockIdx.x * 256 + threadIdx.x;
    const int d4 = (gid & 15) * 4;
    const int s = (gid >> 4) & 2047;
    const int bh = gid >> 15;
    float acc[4] = { 0.f, 0.f, 0.f, 0.f };
    float lsum = 0.f;
#pragma unroll
    for (int k = 0; k < 4; k++) {
        const us4 a = *(const us4*)(Opart + ((size_t)(k * 16 + bh) * 2048 + s) * 64 + d4);
        lsum += lbuf[(size_t)(k * 16 + bh) * 2048 + s];
#pragma unroll
        for (int r = 0; r < 4; r++) acc[r] += b2f(a[r]);
    }
    const float inv = 1.f / lsum;
    us4 out;
#pragma unroll
    for (int r = 0; r < 4; r++) out[r] = f2b(acc[r] * inv);
    const int row = (bh >> 3) * 2048 + s;
    const int col = (bh & 7) * 64 + d4;
    *(us4*)(&O[(size_t)row * 512 + col]) = out;
}

// ------- fused: x' = xf + p0 + p1 + bias ; y = LN(x') (bf16 partials) ------
template<int CN>
__global__ __launch_bounds__(256) void ln_fused(
    const float* __restrict__ Xf, const ushort_t* __restrict__ P0,
    const ushort_t* __restrict__ P1, const float* __restrict__ bias,
    const float* __restrict__ g, const float* __restrict__ beta,
    float* __restrict__ XfOut, ushort_t* __restrict__ Yb, float* __restrict__ Yf)
{
    const int row = blockIdx.x * 4 + (threadIdx.x >> 6);
    const int lane = threadIdx.x & 63;
    const size_t base = (size_t)row * 512;
    float4 x0 = ((const float4*)(Xf + base))[lane];
    float4 x1 = ((const float4*)(Xf + base))[lane + 64];
    const us4 a0 = ((const us4*)(P0 + base))[lane];
    const us4 a1 = ((const us4*)(P0 + base))[lane + 64];
    const us4 c0 = ((const us4*)(P1 + base))[lane];
    const us4 c1 = ((const us4*)(P1 + base))[lane + 64];
    const float4 bb0 = ((const float4*)bias)[lane];
    const float4 bb1 = ((const float4*)bias)[lane + 64];
    x0.x += b2f(a0[0]) + b2f(c0[0]) + bb0.x; x0.y += b2f(a0[1]) + b2f(c0[1]) + bb0.y;
    x0.z += b2f(a0[2]) + b2f(c0[2]) + bb0.z; x0.w += b2f(a0[3]) + b2f(c0[3]) + bb0.w;
    x1.x += b2f(a1[0]) + b2f(c1[0]) + bb1.x; x1.y += b2f(a1[1]) + b2f(c1[1]) + bb1.y;
    x1.z += b2f(a1[2]) + b2f(c1[2]) + bb1.z; x1.w += b2f(a1[3]) + b2f(c1[3]) + bb1.w;

    float s = x0.x + x0.y + x0.z + x0.w + x1.x + x1.y + x1.z + x1.w;
    float s2 = x0.x * x0.x + x0.y * x0.y + x0.z * x0.z + x0.w * x0.w
             + x1.x * x1.x + x1.y * x1.y + x1.z * x1.z + x1.w * x1.w;
#pragma unroll
    for (int m = 1; m < 64; m <<= 1) { s += __shfl_xor(s, m); s2 += __shfl_xor(s2, m); }
    const float mean = s * (1.f / 512.f);
    const float inv = rsqrtf(s2 * (1.f / 512.f) - mean * mean + 1e-5f);
    const float4 g0 = ((const float4*)g)[lane], g1 = ((const float4*)g)[lane + 64];
    const float4 b0 = ((const float4*)beta)[lane], b1 = ((const float4*)beta)[lane + 64];
    float4 y0, y1;
    y0.x = (x0.x - mean) * inv * g0.x + b0.x;
    y0.y = (x0.y - mean) * inv * g0.y + b0.y;
    y0.z = (x0.z - mean) * inv * g0.z + b0.z;
    y0.w = (x0.w - mean) * inv * g0.w + b0.w;
    y1.x = (x1.x - mean) * inv * g1.x + b1.x;
    y1.y = (x1.y - mean) * inv * g1.y + b1.y;
    y1.z = (x1.z - mean) * inv * g1.z + b1.z;
    y1.w = (x1.w - mean) * inv * g1.w + b1.w;
    if constexpr (CN == 0) {
        ((float4*)(XfOut + base))[lane] = x0;
        ((float4*)(XfOut + base))[lane + 64] = x1;
    } else {
        ((float4*)(XfOut + base))[lane] = y0;
        ((float4*)(XfOut + base))[lane + 64] = y1;
        if (Yf) {
            ((float4*)(Yf + base))[lane] = y0;
            ((float4*)(Yf + base))[lane + 64] = y1;
        }
    }
    us4 o0 = { f2b(y0.x), f2b(y0.y), f2b(y0.z), f2b(y0.w) };
    us4 o1 = { f2b(y1.x), f2b(y1.y), f2b(y1.z), f2b(y1.w) };
    ((us4*)(Yb + base))[lane] = o0;
    ((us4*)(Yb + base))[lane + 64] = o1;
}

// ---------------- host ----------------
extern "C" void kernel_launch(void* const* d_in, const int* in_sizes, int n_in,
                              void* d_out, int out_size, void* d_ws, size_t ws_size,
                              hipStream_t stream)
{
    (void)in_sizes; (void)n_in; (void)out_size; (void)ws_size;
    const float* X     = (const float*)d_in[0];
    const float* qkv_w = (const float*)d_in[1];
    const float* qkv_b = (const float*)d_in[2];
    const float* fc_w  = (const float*)d_in[3];
    const float* fc_b  = (const float*)d_in[4];
    const float* ln1_g = (const float*)d_in[5];
    const float* ln1_b = (const float*)d_in[6];
    const float* w1    = (const float*)d_in[7];
    const float* b1    = (const float*)d_in[8];
    const float* w2    = (const float*)d_in[9];
    const float* b2    = (const float*)d_in[10];
    const float* ln2_g = (const float*)d_in[11];
    const float* ln2_b = (const float*)d_in[12];

    char* ws = (char*)d_ws;
    size_t off = 0;
    auto alloc = [&](size_t bytes) -> char* {
        char* p = ws + off;
        off += (bytes + 255) & ~(size_t)255;
        return p;
    };
    ushort_t* qkvw_t = (ushort_t*)alloc(12ull * 1536 * 512 * 2);
    ushort_t* fcw_t  = (ushort_t*)alloc(12ull * 512 * 512 * 2);
    ushort_t* w1_t   = (ushort_t*)alloc(12ull * 512 * 1024 * 2);
    ushort_t* w2_t   = (ushort_t*)alloc(12ull * 1024 * 512 * 2);
    float*    xf     = (float*)   alloc(4096ull * 512 * 4);
    ushort_t* xb     = (ushort_t*)alloc(4096ull * 512 * 2);
    ushort_t* qb     = (ushort_t*)alloc(16ull * 2048 * 64 * 2);   // 4 MB
    ushort_t* kb     = (ushort_t*)alloc(16ull * 2048 * 64 * 2);   // 4 MB
    ushort_t* vt     = (ushort_t*)alloc(16ull * 64 * 2048 * 2);
    ushort_t* ob     = (ushort_t*)alloc(4096ull * 512 * 2);
    ushort_t* y1     = (ushort_t*)alloc(4096ull * 512 * 2);
    ushort_t* hbuf   = (ushort_t*)alloc(4096ull * 1024 * 2);
    ushort_t* opart  = (ushort_t*)alloc(64ull * 2048 * 64 * 2);   // 16 MB
    float*    lbuf   = (float*)   alloc(64ull * 2048 * 4);
    ushort_t* pk0 = qb;
    ushort_t* pk1 = kb;

    transpose_cvt<<<dim3(48, 16, 12), 256, 0, stream>>>(qkv_w, qkvw_t, 512, 1536);
    transpose_cvt<<<dim3(16, 16, 12), 256, 0, stream>>>(fc_w, fcw_t, 512, 512);
    transpose_cvt<<<dim3(32, 16, 12), 256, 0, stream>>>(w1, w1_t, 512, 1024);
    transpose_cvt<<<dim3(16, 32, 12), 256, 0, stream>>>(w2, w2_t, 1024, 512);
    init_x<<<2048, 256, 0, stream>>>(X, xf, xb);

    const float sl2 = (float)(0.044194173824159216 * 1.4426950408889634); // scale*log2(e)
    for (int nb = 0; nb < 12; nb++) {
        gemm128_qkv<<<32 * 12, 256, 0, stream>>>(
            xb, qkvw_t + (size_t)nb * 1536 * 512, qkv_b + nb * 1536,
            qb, kb, vt, 4096, 1536, 512, sl2);
        flash_attn11<<<1024, 256, 0, stream>>>(qb, kb, vt, opart, lbuf, 4);
        combine_attn<<<2048, 256, 0, stream>>>(opart, lbuf, ob);
        gemm64_splitk<<<64 * 4 * 2, 256, 0, stream>>>(
            ob, fcw_t + (size_t)nb * 512 * 512, pk0, pk1, 4096, 512, 512);
        ln_fused<0><<<1024, 256, 0, stream>>>(
            xf, pk0, pk1, fc_b + nb * 512, ln1_g + nb * 512, ln1_b + nb * 512,
            xf, y1, nullptr);
        gemm64<EPI_RELUB><<<64 * 8, 256, 0, stream>>>(
            y1, w1_t + (size_t)nb * 1024 * 512, b1 + nb * 1024,
            hbuf, 4096, 1024, 512);
        gemm64_splitk<<<64 * 4 * 2, 256, 0, stream>>>(
            hbuf, w2_t + (size_t)nb * 1024 * 512, pk0, pk1, 4096, 512, 1024);
        ln_fused<1><<<1024, 256, 0, stream>>>(
            xf, pk0, pk1, b2 + nb * 512, ln2_g + nb * 512, ln2_b + nb * 512,
            xf, xb, nb == 11 ? (float*)d_out : nullptr);
    }
}

// Round 15
// 1123.032 us; speedup vs baseline: 1.2840x; 1.0252x over previous
//
#include <hip/hip_runtime.h>

typedef unsigned short ushort_t;
typedef __attribute__((ext_vector_type(8))) short bf16x8;
typedef __attribute__((ext_vector_type(4))) float f32x4;
typedef __attribute__((ext_vector_type(4))) unsigned short us4;

#define DEV __device__ __forceinline__

DEV ushort_t f2b(float f) {
    union { float f; unsigned u; } x; x.f = f;
    unsigned r = (x.u + 0x7fffu + ((x.u >> 16) & 1u)) >> 16;
    return (ushort_t)r;
}

DEV float b2f(ushort_t u) {
    union { unsigned u; float f; } x; x.u = ((unsigned)u) << 16;
    return x.f;
}

DEV unsigned cvt_pk_bf16(float lo, float hi) {
    unsigned r;
    asm("v_cvt_pk_bf16_f32 %0, %1, %2" : "=v"(r) : "v"(lo), "v"(hi));
    return r;
}

typedef void __attribute__((address_space(1)))* gp1;
typedef void __attribute__((address_space(3)))* sp3;
DEV void gload_lds16(const void* g, void* l) {
    __builtin_amdgcn_global_load_lds((gp1)g, (sp3)l, 16, 0, 0);
}

// ---------------- weight prep: f32 [K][N] -> bf16 [N][K] ----------------
__global__ __launch_bounds__(256) void transpose_cvt(
    const float* __restrict__ in, ushort_t* __restrict__ out, int K, int N)
{
    __shared__ float tile[32][33];
    const int nb = blockIdx.z;
    const float* src = in + (size_t)nb * K * N;
    ushort_t* dst = out + (size_t)nb * K * N;
    const int n0 = blockIdx.x * 32, k0 = blockIdx.y * 32;
    const int tx = threadIdx.x & 31, ty = threadIdx.x >> 5;
#pragma unroll
    for (int i = 0; i < 32; i += 8)
        tile[ty + i][tx] = src[(size_t)(k0 + ty + i) * N + n0 + tx];
    __syncthreads();
#pragma unroll
    for (int i = 0; i < 32; i += 8)
        dst[(size_t)(n0 + ty + i) * K + k0 + tx] = f2b(tile[tx][ty + i]);
}

// ---------------- init: X f32 -> xf f32 copy + xb bf16 ----------------
__global__ __launch_bounds__(256) void init_x(
    const float* __restrict__ X, float* __restrict__ xf, ushort_t* __restrict__ xb)
{
    const int i = blockIdx.x * 256 + threadIdx.x;
    const float4 v = ((const float4*)X)[i];
    ((float4*)xf)[i] = v;
    us4 o = { f2b(v.x), f2b(v.y), f2b(v.z), f2b(v.w) };
    ((us4*)xb)[i] = o;
}

enum { EPI_QKV = 0, EPI_RELUB = 2 };

// ---------------- GEMM 64x128 tile, BK=64 (QKV / MLP1) ---------------------
template<int EPI>
__global__ __launch_bounds__(256, 3) void gemm64(
    const ushort_t* __restrict__ A, const ushort_t* __restrict__ Wt,
    const float* __restrict__ bias, ushort_t* __restrict__ Cb,
    ushort_t* __restrict__ Oq, ushort_t* __restrict__ Ok, ushort_t* __restrict__ Ov,
    int M, int N, int K, float qs)
{
    __shared__ __align__(16) ushort_t lA[2][64 * 64];
    __shared__ __align__(16) ushort_t lB[2][128 * 64];
    const int nbm = M >> 6;
    const int bm = blockIdx.x % nbm;
    const int bn = blockIdx.x / nbm;
    const int tid = threadIdx.x, lane = tid & 63, w = tid >> 6;
    const int l15 = lane & 15, l4 = lane >> 4;

    f32x4 acc[4][2];
#pragma unroll
    for (int i = 0; i < 4; i++)
#pragma unroll
        for (int j = 0; j < 2; j++) { f32x4 z = {0.f, 0.f, 0.f, 0.f}; acc[i][j] = z; }

    const int srow = tid >> 3;
    const int sch = tid & 7;
    const int swch = sch ^ (srow & 7);
    const ushort_t* Asrc0 = A  + (size_t)(bm * 64 + srow) * K + swch * 8;
    const ushort_t* Asrc1 = A  + (size_t)(bm * 64 + srow + 32) * K + swch * 8;
    const ushort_t* Bsrc0 = Wt + (size_t)(bn * 128 + srow) * K + swch * 8;
    const ushort_t* Bsrc1 = Wt + (size_t)(bn * 128 + srow + 32) * K + swch * 8;
    const ushort_t* Bsrc2 = Wt + (size_t)(bn * 128 + srow + 64) * K + swch * 8;
    const ushort_t* Bsrc3 = Wt + (size_t)(bn * 128 + srow + 96) * K + swch * 8;
    char* lAc = (char*)lA;
    char* lBc = (char*)lB;

#define GE_STAGE(buf, k0) do {                                            \
        gload_lds16(Asrc0 + (k0), lAc + (buf) * 8192  + w * 1024);        \
        gload_lds16(Asrc1 + (k0), lAc + (buf) * 8192  + 4096 + w * 1024); \
        gload_lds16(Bsrc0 + (k0), lBc + (buf) * 16384 + w * 1024);        \
        gload_lds16(Bsrc1 + (k0), lBc + (buf) * 16384 + 4096 + w * 1024); \
        gload_lds16(Bsrc2 + (k0), lBc + (buf) * 16384 + 8192 + w * 1024); \
        gload_lds16(Bsrc3 + (k0), lBc + (buf) * 16384 + 12288 + w * 1024);\
    } while (0)

    GE_STAGE(0, 0);
    __syncthreads();

    const int nIt = K >> 6;
    int cur = 0;
    for (int it = 0; it < nIt; ++it) {
        if (it + 1 < nIt) GE_STAGE(cur ^ 1, (it + 1) * 64);
#pragma unroll
        for (int ks = 0; ks < 2; ks++) {
            bf16x8 af[4], bfr[2];
#pragma unroll
            for (int i = 0; i < 4; i++) {
                const int row = i * 16 + l15;
                af[i] = *(const bf16x8*)(lAc + cur * 8192 + row * 128 +
                                         (((ks * 4 + l4) ^ (row & 7)) << 4));
            }
#pragma unroll
            for (int j = 0; j < 2; j++) {
                const int row = w * 32 + j * 16 + l15;
                bfr[j] = *(const bf16x8*)(lBc + cur * 16384 + row * 128 +
                                          (((ks * 4 + l4) ^ (row & 7)) << 4));
            }
#pragma unroll
            for (int i = 0; i < 4; i++)
#pragma unroll
                for (int j = 0; j < 2; j++)
                    acc[i][j] = __builtin_amdgcn_mfma_f32_16x16x32_bf16(af[i], bfr[j], acc[i][j], 0, 0, 0);
        }
        __syncthreads();
        cur ^= 1;
    }
#undef GE_STAGE

    const int mbase = bm * 64;
    const int nbase = bn * 128 + w * 32;
#pragma unroll
    for (int j = 0; j < 2; j++) {
        const int nf16 = nbase + j * 16;
        const float bv = bias[nf16 + l15];
        if constexpr (EPI == EPI_QKV) {
            const int head = nf16 / 192;
            const int rem = nf16 - head * 192;
            const int part = rem >> 6;
            const int dh = (rem & 63) + l15;
#pragma unroll
            for (int i = 0; i < 4; i++) {
                const int m0 = mbase + i * 16 + l4 * 4;
                const int b = m0 >> 11, s0 = m0 & 2047;
                if (part == 2) {
                    us4 pv;
#pragma unroll
                    for (int r = 0; r < 4; r++) pv[r] = f2b(acc[i][j][r] + bv);
                    *(us4*)(&Ov[((size_t)(b * 8 + head) * 64 + dh) * 2048 + s0]) = pv;
                } else if (part == 0) {
#pragma unroll
                    for (int r = 0; r < 4; r++)
                        Oq[((size_t)(b * 8 + head) * 2048 + s0 + r) * 64 + dh] =
                            f2b((acc[i][j][r] + bv) * qs);
                } else {
#pragma unroll
                    for (int r = 0; r < 4; r++)
                        Ok[((size_t)(b * 8 + head) * 2048 + s0 + r) * 64 + dh] =
                            f2b(acc[i][j][r] + bv);
                }
            }
        } else {
#pragma unroll
            for (int i = 0; i < 4; i++) {
                const int m0 = mbase + i * 16 + l4 * 4;
#pragma unroll
                for (int r = 0; r < 4; r++) {
                    const size_t idx = (size_t)(m0 + r) * N + nf16 + l15;
                    const float v = acc[i][j][r] + bv;
                    Cb[idx] = f2b(v > 0.f ? v : 0.f);
                }
            }
        }
    }
}

// ---------------- GEMM 64x128, split-K=2, writes bf16 partials --------------
__global__ __launch_bounds__(256, 2) void gemm64_splitk(
    const ushort_t* __restrict__ A, const ushort_t* __restrict__ Wt,
    ushort_t* __restrict__ P0, ushort_t* __restrict__ P1, int M, int N, int K)
{
    __shared__ __align__(16) ushort_t lA[2][64 * 64];
    __shared__ __align__(16) ushort_t lB[2][128 * 64];
    const int nbm = M >> 6;
    const int nbn = N >> 7;
    int bid = blockIdx.x;
    const int bm = bid % nbm; bid /= nbm;
    const int bn = bid % nbn;
    const int kh = bid / nbn;
    const int Keff = K >> 1;
    const int kbase = kh * Keff;
    const int tid = threadIdx.x, lane = tid & 63, w = tid >> 6;
    const int l15 = lane & 15, l4 = lane >> 4;

    f32x4 acc[4][2];
#pragma unroll
    for (int i = 0; i < 4; i++)
#pragma unroll
        for (int j = 0; j < 2; j++) { f32x4 z = {0.f, 0.f, 0.f, 0.f}; acc[i][j] = z; }

    const int srow = tid >> 3;
    const int sch = tid & 7;
    const int swch = sch ^ (srow & 7);
    const ushort_t* Asrc0 = A  + (size_t)(bm * 64 + srow) * K + kbase + swch * 8;
    const ushort_t* Asrc1 = A  + (size_t)(bm * 64 + srow + 32) * K + kbase + swch * 8;
    const ushort_t* Bsrc0 = Wt + (size_t)(bn * 128 + srow) * K + kbase + swch * 8;
    const ushort_t* Bsrc1 = Wt + (size_t)(bn * 128 + srow + 32) * K + kbase + swch * 8;
    const ushort_t* Bsrc2 = Wt + (size_t)(bn * 128 + srow + 64) * K + kbase + swch * 8;
    const ushort_t* Bsrc3 = Wt + (size_t)(bn * 128 + srow + 96) * K + kbase + swch * 8;
    char* lAc = (char*)lA;
    char* lBc = (char*)lB;

#define GE_STAGE(buf, k0) do {                                            \
        gload_lds16(Asrc0 + (k0), lAc + (buf) * 8192  + w * 1024);        \
        gload_lds16(Asrc1 + (k0), lAc + (buf) * 8192  + 4096 + w * 1024); \
        gload_lds16(Bsrc0 + (k0), lBc + (buf) * 16384 + w * 1024);        \
        gload_lds16(Bsrc1 + (k0), lBc + (buf) * 16384 + 4096 + w * 1024); \
        gload_lds16(Bsrc2 + (k0), lBc + (buf) * 16384 + 8192 + w * 1024); \
        gload_lds16(Bsrc3 + (k0), lBc + (buf) * 16384 + 12288 + w * 1024);\
    } while (0)

    GE_STAGE(0, 0);
    __syncthreads();

    const int nIt = Keff >> 6;
    int cur = 0;
    for (int it = 0; it < nIt; ++it) {
        if (it + 1 < nIt) GE_STAGE(cur ^ 1, (it + 1) * 64);
#pragma unroll
        for (int ks = 0; ks < 2; ks++) {
            bf16x8 af[4], bfr[2];
#pragma unroll
            for (int i = 0; i < 4; i++) {
                const int row = i * 16 + l15;
                af[i] = *(const bf16x8*)(lAc + cur * 8192 + row * 128 +
                                         (((ks * 4 + l4) ^ (row & 7)) << 4));
            }
#pragma unroll
            for (int j = 0; j < 2; j++) {
                const int row = w * 32 + j * 16 + l15;
                bfr[j] = *(const bf16x8*)(lBc + cur * 16384 + row * 128 +
                                          (((ks * 4 + l4) ^ (row & 7)) << 4));
            }
#pragma unroll
            for (int i = 0; i < 4; i++)
#pragma unroll
                for (int j = 0; j < 2; j++)
                    acc[i][j] = __builtin_amdgcn_mfma_f32_16x16x32_bf16(af[i], bfr[j], acc[i][j], 0, 0, 0);
        }
        __syncthreads();
        cur ^= 1;
    }
#undef GE_STAGE

    ushort_t* out = kh ? P1 : P0;
    const int mbase = bm * 64;
    const int nbase = bn * 128 + w * 32;
#pragma unroll
    for (int j = 0; j < 2; j++) {
        const int nf16 = nbase + j * 16;
#pragma unroll
        for (int i = 0; i < 4; i++) {
            const int m0 = mbase + i * 16 + l4 * 4;
#pragma unroll
            for (int r = 0; r < 4; r++)
                out[(size_t)(m0 + r) * N + nf16 + l15] = f2b(acc[i][j][r]);
        }
    }
}

// ---------------- flash attention v11: v7 2-qi body + KV-split 4, 40 KB ----
__global__ __launch_bounds__(256, 4) void flash_attn11(
    const ushort_t* __restrict__ Q, const ushort_t* __restrict__ Kg,
    const ushort_t* __restrict__ Vg, ushort_t* __restrict__ Opart,
    float* __restrict__ lbuf, int niter)
{
    __shared__ __align__(16) ushort_t lK[2][64 * 64];
    __shared__ __align__(16) ushort_t lV[2][64 * 64];
    __shared__ __align__(16) ushort_t lP[4][16 * 64];

    const int id = blockIdx.x;
    const int rest = id >> 3;
    const int kvh = rest & 3;
    const int qt = (rest >> 2) & 15;
    const int bh = (id & 7) + ((rest >> 6) << 3);
    const int tid = threadIdx.x, lane = tid & 63, w = tid >> 6;
    const int l15 = lane & 15, l4 = lane >> 4;
    const int qrow0 = qt * 128 + w * 32;

    const ushort_t* Qb = Q + ((size_t)bh * 2048 + qrow0) * 64;
    bf16x8 qf[2][2];
#pragma unroll
    for (int qi = 0; qi < 2; qi++)
#pragma unroll
        for (int ks = 0; ks < 2; ks++)
            qf[qi][ks] = *(const bf16x8*)(Qb + (qi * 16 + l15) * 64 + ks * 32 + l4 * 8);

    const ushort_t* Kbase = Kg + (size_t)bh * 2048 * 64;
    const ushort_t* Vbase = Vg + (size_t)bh * 64 * 2048;

    const f32x4 FZ = { 0.f, 0.f, 0.f, 0.f };
    float l_run[2] = { 0.f, 0.f };
    f32x4 oacc[2][4];
#pragma unroll
    for (int qi = 0; qi < 2; qi++)
#pragma unroll
        for (int nd = 0; nd < 4; nd++) oacc[qi][nd] = FZ;

    char* lKc = (char*)lK;
    char* lVc = (char*)lV;
    char* myP = (char*)(lP[w]);

    const int srow8 = lane >> 3;
    const int sch = lane & 7;

#define FA_STAGE(buf, kt) do {                                              \
        const int row0_ = w * 16 + srow8;                                   \
        const int sc0_ = sch ^ (row0_ & 7);                                 \
        gload_lds16(Kbase + (size_t)((kt) * 64 + row0_) * 64 + sc0_ * 8,    \
                    lKc + (buf) * 8192 + w * 2048);                         \
        gload_lds16(Vbase + (size_t)row0_ * 2048 + (kt) * 64 + sc0_ * 8,    \
                    lVc + (buf) * 8192 + w * 2048);                         \
        gload_lds16(Kbase + (size_t)((kt) * 64 + row0_ + 8) * 64 + sc0_ * 8,\
                    lKc + (buf) * 8192 + w * 2048 + 1024);                  \
        gload_lds16(Vbase + (size_t)(row0_ + 8) * 2048 + (kt) * 64 + sc0_ * 8,\
                    lVc + (buf) * 8192 + w * 2048 + 1024);                  \
    } while (0)

#define FA_BODY(CUR, IT, LIM) do {                                          \
    if ((IT) < (LIM)) FA_STAGE((CUR) ^ 1, kt0 + (IT) + 1);                  \
    f32x4 sc[2][4];                                                         \
    __builtin_amdgcn_s_setprio(1);                                          \
    _Pragma("unroll")                                                       \
    for (int nf = 0; nf < 4; nf++) {                                        \
        const int krow = nf * 16 + l15;                                     \
        const bf16x8 kf0 = *(const bf16x8*)(lKc + (CUR) * 8192 + krow * 128 + \
                                            ((l4 ^ (krow & 7)) << 4));      \
        const bf16x8 kf1 = *(const bf16x8*)(lKc + (CUR) * 8192 + krow * 128 + \
                                            (((4 + l4) ^ (krow & 7)) << 4)); \
        sc[0][nf] = __builtin_amdgcn_mfma_f32_16x16x32_bf16(kf0, qf[0][0], FZ, 0, 0, 0); \
        sc[1][nf] = __builtin_amdgcn_mfma_f32_16x16x32_bf16(kf0, qf[1][0], FZ, 0, 0, 0); \
        sc[0][nf] = __builtin_amdgcn_mfma_f32_16x16x32_bf16(kf1, qf[0][1], sc[0][nf], 0, 0, 0); \
        sc[1][nf] = __builtin_amdgcn_mfma_f32_16x16x32_bf16(kf1, qf[1][1], sc[1][nf], 0, 0, 0); \
    }                                                                       \
    __builtin_amdgcn_s_setprio(0);                                          \
    _Pragma("unroll")                                                       \
    for (int qi = 0; qi < 2; qi++) {                                        \
        float ps0 = 0.f, ps1 = 0.f;                                         \
        _Pragma("unroll")                                                   \
        for (int nf = 0; nf < 4; nf++) {                                    \
            const float p0 = exp2f(sc[qi][nf][0]);                          \
            const float p1 = exp2f(sc[qi][nf][1]);                          \
            const float p2 = exp2f(sc[qi][nf][2]);                          \
            const float p3 = exp2f(sc[qi][nf][3]);                          \
            sc[qi][nf][0] = p0; sc[qi][nf][1] = p1;                         \
            sc[qi][nf][2] = p2; sc[qi][nf][3] = p3;                         \
            ps0 += p0 + p2; ps1 += p1 + p3;                                 \
        }                                                                   \
        l_run[qi] += ps0 + ps1;                                             \
    }                                                                       \
    const int hh0 = (l15 >> 3) & 1;                                         \
    char* rp = myP + l15 * 128;                                             \
    const int swz = (l15 & 7) << 4;                                         \
    bf16x8 pa[2][2];                                                        \
    _Pragma("unroll")                                                       \
    for (int nf = 0; nf < 4; nf++) {                                        \
        const unsigned pw0 = cvt_pk_bf16(sc[0][nf][0], sc[0][nf][1]);       \
        const unsigned pw1 = cvt_pk_bf16(sc[0][nf][2], sc[0][nf][3]);       \
        const unsigned wA = hh0 ? pw1 : pw0;                                \
        const unsigned wB = hh0 ? pw0 : pw1;                                \
        const int cbase = nf * 32 + l4 * 8;                                 \
        *(unsigned*)(rp + ((cbase + hh0 * 4) ^ swz)) = wA;                  \
        *(unsigned*)(rp + ((cbase + (1 - hh0) * 4) ^ swz)) = wB;            \
    }                                                                       \
    __asm__ volatile("" ::: "memory");                                     \
    pa[0][0] = *(const bf16x8*)(myP + l15 * 128 + ((l4 * 16) ^ swz));       \
    pa[0][1] = *(const bf16x8*)(myP + l15 * 128 + ((64 + l4 * 16) ^ swz));  \
    __asm__ volatile("" ::: "memory");                                     \
    _Pragma("unroll")                                                       \
    for (int nf = 0; nf < 4; nf++) {                                        \
        const unsigned pw0 = cvt_pk_bf16(sc[1][nf][0], sc[1][nf][1]);       \
        const unsigned pw1 = cvt_pk_bf16(sc[1][nf][2], sc[1][nf][3]);       \
        const unsigned wA = hh0 ? pw1 : pw0;                                \
        const unsigned wB = hh0 ? pw0 : pw1;                                \
        const int cbase = nf * 32 + l4 * 8;                                 \
        *(unsigned*)(rp + ((cbase + hh0 * 4) ^ swz)) = wA;                  \
        *(unsigned*)(rp + ((cbase + (1 - hh0) * 4) ^ swz)) = wB;            \
    }                                                                       \
    __asm__ volatile("" ::: "memory");                                     \
    pa[1][0] = *(const bf16x8*)(myP + l15 * 128 + ((l4 * 16) ^ swz));       \
    pa[1][1] = *(const bf16x8*)(myP + l15 * 128 + ((64 + l4 * 16) ^ swz));  \
    __asm__ volatile("" ::: "memory");                                     \
    __builtin_amdgcn_s_setprio(1);                                          \
    _Pragma("unroll")                                                       \
    for (int ks = 0; ks < 2; ks++)                                          \
        _Pragma("unroll")                                                   \
        for (int nd = 0; nd < 4; nd++) {                                    \
            const int vrow = nd * 16 + l15;                                 \
            const bf16x8 vf = *(const bf16x8*)(lVc + (CUR) * 8192 + vrow * 128 + \
                                               (((ks * 4 + l4) ^ (vrow & 7)) << 4)); \
            oacc[0][nd] = __builtin_amdgcn_mfma_f32_16x16x32_bf16(pa[0][ks], vf, oacc[0][nd], 0, 0, 0); \
            oacc[1][nd] = __builtin_amdgcn_mfma_f32_16x16x32_bf16(pa[1][ks], vf, oacc[1][nd], 0, 0, 0); \
        }                                                                   \
    __builtin_amdgcn_s_setprio(0);                                          \
    __syncthreads();                                                        \
} while (0)

    const int kt0 = kvh * 8;
    FA_STAGE(0, kt0);
    __syncthreads();

    const int lim = niter * 2 - 1;
#pragma unroll 1
    for (int it2 = 0; it2 < niter; ++it2) {
        FA_BODY(0, it2 * 2, lim);
        FA_BODY(1, it2 * 2 + 1, lim);
    }
#undef FA_BODY
#undef FA_STAGE

#pragma unroll
    for (int qi = 0; qi < 2; qi++) {
        l_run[qi] += __shfl_xor(l_run[qi], 16);
        l_run[qi] += __shfl_xor(l_run[qi], 32);
    }
    ushort_t* Op = Opart + ((size_t)(kvh * 16 + bh) * 2048 + qrow0) * 64;
#pragma unroll
    for (int qi = 0; qi < 2; qi++)
#pragma unroll
        for (int r = 0; r < 4; r++)
#pragma unroll
            for (int nd = 0; nd < 4; nd++)
                Op[(size_t)(qi * 16 + l4 * 4 + r) * 64 + nd * 16 + l15] =
                    f2b(oacc[qi][nd][r]);
    if (lane < 32) {
        const int qi = lane >> 4;
        lbuf[(size_t)(kvh * 16 + bh) * 2048 + qrow0 + qi * 16 + (lane & 15)] =
            qi ? l_run[1] : l_run[0];
    }
}

// ---------------- combine the four KV quarters (l-weighted sum) -------------
__global__ __launch_bounds__(256) void combine_attn(
    const ushort_t* __restrict__ Opart, const float* __restrict__ lbuf,
    ushort_t* __restrict__ O)
{
    const int gid = blockIdx.x * 256 + threadIdx.x;
    const int d4 = (gid & 15) * 4;
    const int s = (gid >> 4) & 2047;
    const int bh = gid >> 15;
    float acc[4] = { 0.f, 0.f, 0.f, 0.f };
    float lsum = 0.f;
#pragma unroll
    for (int k = 0; k < 4; k++) {
        const us4 a = *(const us4*)(Opart + ((size_t)(k * 16 + bh) * 2048 + s) * 64 + d4);
        lsum += lbuf[(size_t)(k * 16 + bh) * 2048 + s];
#pragma unroll
        for (int r = 0; r < 4; r++) acc[r] += b2f(a[r]);
    }
    const float inv = 1.f / lsum;
    us4 out;
#pragma unroll
    for (int r = 0; r < 4; r++) out[r] = f2b(acc[r] * inv);
    const int row = (bh >> 3) * 2048 + s;
    const int col = (bh & 7) * 64 + d4;
    *(us4*)(&O[(size_t)row * 512 + col]) = out;
}

// ------- fused: x' = xf + p0 + p1 + bias ; y = LN(x') (bf16 partials) ------
template<int CN>
__global__ __launch_bounds__(256) void ln_fused(
    const float* __restrict__ Xf, const ushort_t* __restrict__ P0,
    const ushort_t* __restrict__ P1, const float* __restrict__ bias,
    const float* __restrict__ g, const float* __restrict__ beta,
    float* __restrict__ XfOut, ushort_t* __restrict__ Yb, float* __restrict__ Yf)
{
    const int row = blockIdx.x * 4 + (threadIdx.x >> 6);
    const int lane = threadIdx.x & 63;
    const size_t base = (size_t)row * 512;
    float4 x0 = ((const float4*)(Xf + base))[lane];
    float4 x1 = ((const float4*)(Xf + base))[lane + 64];
    const us4 a0 = ((const us4*)(P0 + base))[lane];
    const us4 a1 = ((const us4*)(P0 + base))[lane + 64];
    const us4 c0 = ((const us4*)(P1 + base))[lane];
    const us4 c1 = ((const us4*)(P1 + base))[lane + 64];
    const float4 bb0 = ((const float4*)bias)[lane];
    const float4 bb1 = ((const float4*)bias)[lane + 64];
    x0.x += b2f(a0[0]) + b2f(c0[0]) + bb0.x; x0.y += b2f(a0[1]) + b2f(c0[1]) + bb0.y;
    x0.z += b2f(a0[2]) + b2f(c0[2]) + bb0.z; x0.w += b2f(a0[3]) + b2f(c0[3]) + bb0.w;
    x1.x += b2f(a1[0]) + b2f(c1[0]) + bb1.x; x1.y += b2f(a1[1]) + b2f(c1[1]) + bb1.y;
    x1.z += b2f(a1[2]) + b2f(c1[2]) + bb1.z; x1.w += b2f(a1[3]) + b2f(c1[3]) + bb1.w;

    float s = x0.x + x0.y + x0.z + x0.w + x1.x + x1.y + x1.z + x1.w;
    float s2 = x0.x * x0.x + x0.y * x0.y + x0.z * x0.z + x0.w * x0.w
             + x1.x * x1.x + x1.y * x1.y + x1.z * x1.z + x1.w * x1.w;
#pragma unroll
    for (int m = 1; m < 64; m <<= 1) { s += __shfl_xor(s, m); s2 += __shfl_xor(s2, m); }
    const float mean = s * (1.f / 512.f);
    const float inv = rsqrtf(s2 * (1.f / 512.f) - mean * mean + 1e-5f);
    const float4 g0 = ((const float4*)g)[lane], g1 = ((const float4*)g)[lane + 64];
    const float4 b0 = ((const float4*)beta)[lane], b1 = ((const float4*)beta)[lane + 64];
    float4 y0, y1;
    y0.x = (x0.x - mean) * inv * g0.x + b0.x;
    y0.y = (x0.y - mean) * inv * g0.y + b0.y;
    y0.z = (x0.z - mean) * inv * g0.z + b0.z;
    y0.w = (x0.w - mean) * inv * g0.w + b0.w;
    y1.x = (x1.x - mean) * inv * g1.x + b1.x;
    y1.y = (x1.y - mean) * inv * g1.y + b1.y;
    y1.z = (x1.z - mean) * inv * g1.z + b1.z;
    y1.w = (x1.w - mean) * inv * g1.w + b1.w;
    if constexpr (CN == 0) {
        ((float4*)(XfOut + base))[lane] = x0;
        ((float4*)(XfOut + base))[lane + 64] = x1;
    } else {
        ((float4*)(XfOut + base))[lane] = y0;
        ((float4*)(XfOut + base))[lane + 64] = y1;
        if (Yf) {
            ((float4*)(Yf + base))[lane] = y0;
            ((float4*)(Yf + base))[lane + 64] = y1;
        }
    }
    us4 o0 = { f2b(y0.x), f2b(y0.y), f2b(y0.z), f2b(y0.w) };
    us4 o1 = { f2b(y1.x), f2b(y1.y), f2b(y1.z), f2b(y1.w) };
    ((us4*)(Yb + base))[lane] = o0;
    ((us4*)(Yb + base))[lane + 64] = o1;
}

// ---------------- host ----------------
extern "C" void kernel_launch(void* const* d_in, const int* in_sizes, int n_in,
                              void* d_out, int out_size, void* d_ws, size_t ws_size,
                              hipStream_t stream)
{
    (void)in_sizes; (void)n_in; (void)out_size; (void)ws_size;
    const float* X     = (const float*)d_in[0];
    const float* qkv_w = (const float*)d_in[1];
    const float* qkv_b = (const float*)d_in[2];
    const float* fc_w  = (const float*)d_in[3];
    const float* fc_b  = (const float*)d_in[4];
    const float* ln1_g = (const float*)d_in[5];
    const float* ln1_b = (const float*)d_in[6];
    const float* w1    = (const float*)d_in[7];
    const float* b1    = (const float*)d_in[8];
    const float* w2    = (const float*)d_in[9];
    const float* b2    = (const float*)d_in[10];
    const float* ln2_g = (const float*)d_in[11];
    const float* ln2_b = (const float*)d_in[12];

    char* ws = (char*)d_ws;
    size_t off = 0;
    auto alloc = [&](size_t bytes) -> char* {
        char* p = ws + off;
        off += (bytes + 255) & ~(size_t)255;
        return p;
    };
    ushort_t* qkvw_t = (ushort_t*)alloc(12ull * 1536 * 512 * 2);
    ushort_t* fcw_t  = (ushort_t*)alloc(12ull * 512 * 512 * 2);
    ushort_t* w1_t   = (ushort_t*)alloc(12ull * 512 * 1024 * 2);
    ushort_t* w2_t   = (ushort_t*)alloc(12ull * 1024 * 512 * 2);
    float*    xf     = (float*)   alloc(4096ull * 512 * 4);
    ushort_t* xb     = (ushort_t*)alloc(4096ull * 512 * 2);
    ushort_t* qb     = (ushort_t*)alloc(16ull * 2048 * 64 * 2);   // 4 MB
    ushort_t* kb     = (ushort_t*)alloc(16ull * 2048 * 64 * 2);   // 4 MB
    ushort_t* vt     = (ushort_t*)alloc(16ull * 64 * 2048 * 2);
    ushort_t* ob     = (ushort_t*)alloc(4096ull * 512 * 2);
    ushort_t* y1     = (ushort_t*)alloc(4096ull * 512 * 2);
    ushort_t* hbuf   = (ushort_t*)alloc(4096ull * 1024 * 2);
    ushort_t* opart  = (ushort_t*)alloc(64ull * 2048 * 64 * 2);   // 16 MB
    float*    lbuf   = (float*)   alloc(64ull * 2048 * 4);
    // split-K bf16 partials alias qb/kb (dead between flash-consume and next QKV)
    ushort_t* pk0 = qb;
    ushort_t* pk1 = kb;

    transpose_cvt<<<dim3(48, 16, 12), 256, 0, stream>>>(qkv_w, qkvw_t, 512, 1536);
    transpose_cvt<<<dim3(16, 16, 12), 256, 0, stream>>>(fc_w, fcw_t, 512, 512);
    transpose_cvt<<<dim3(32, 16, 12), 256, 0, stream>>>(w1, w1_t, 512, 1024);
    transpose_cvt<<<dim3(16, 32, 12), 256, 0, stream>>>(w2, w2_t, 1024, 512);
    init_x<<<2048, 256, 0, stream>>>(X, xf, xb);

    const float sl2 = (float)(0.044194173824159216 * 1.4426950408889634); // scale*log2(e)
    for (int nb = 0; nb < 12; nb++) {
        gemm64<EPI_QKV><<<64 * 12, 256, 0, stream>>>(
            xb, qkvw_t + (size_t)nb * 1536 * 512, qkv_b + nb * 1536,
            nullptr, qb, kb, vt, 4096, 1536, 512, sl2);
        flash_attn11<<<1024, 256, 0, stream>>>(qb, kb, vt, opart, lbuf, 4);
        combine_attn<<<2048, 256, 0, stream>>>(opart, lbuf, ob);
        gemm64_splitk<<<64 * 4 * 2, 256, 0, stream>>>(
            ob, fcw_t + (size_t)nb * 512 * 512, pk0, pk1, 4096, 512, 512);
        ln_fused<0><<<1024, 256, 0, stream>>>(
            xf, pk0, pk1, fc_b + nb * 512, ln1_g + nb * 512, ln1_b + nb * 512,
            xf, y1, nullptr);
        gemm64<EPI_RELUB><<<64 * 8, 256, 0, stream>>>(
            y1, w1_t + (size_t)nb * 1024 * 512, b1 + nb * 1024,
            hbuf, nullptr, nullptr, nullptr, 4096, 1024, 512, 1.f);
        gemm64_splitk<<<64 * 4 * 2, 256, 0, stream>>>(
            hbuf, w2_t + (size_t)nb * 1024 * 512, pk0, pk1, 4096, 512, 1024);
        ln_fused<1><<<1024, 256, 0, stream>>>(
            xf, pk0, pk1, b2 + nb * 512, ln2_g + nb * 512, ln2_b + nb * 512,
            xf, xb, nb == 11 ? (float*)d_out : nullptr);
    }
}